// Round 1
// baseline (1698.256 us; speedup 1.0000x reference)
//
#include <hip/hip_runtime.h>
#include <cstddef>

#define S_LEN   1024
#define DMODEL  1024
#define NHEADS  16
#define HDIM    64
#define NBATCH  8
#define MROWS   (NBATCH * S_LEN)   // 8192
#define NBH     (NBATCH * NHEADS)  // 128

// ---------------------------------------------------------------------------
// Projection GEMM: Y = X @ W^T + bias
//   X: [M, 1024] row-major, W: [1024, 1024] row-major (N,K) -> both K-contiguous
//   head_major=1: write Y at [(b*NH+h)*S + s]*64 + d   (Q/K/V, [B,H,S,Dh])
//   head_major=0: write Y at m*1024 + n                (output proj)
// 64x64 tile, TK=32, 256 threads, 4x4 per-thread microtile.
// LDS tiles stored k-major (transposed) with +4 pad -> ds_read_b128 compute reads.
// ---------------------------------------------------------------------------
__global__ __launch_bounds__(256) void proj_gemm_k(
    const float* __restrict__ X, const float* __restrict__ W,
    const float* __restrict__ bias, float* __restrict__ Y, int head_major)
{
  constexpr int TM = 64, TN = 64, TK = 32, Kd = DMODEL;
  __shared__ __align__(16) float As[TK][TM + 4];
  __shared__ __align__(16) float Bs[TK][TN + 4];
  const int t  = threadIdx.x;
  const int tx = t & 15, ty = t >> 4;
  const int bm = blockIdx.x * TM;
  const int bn = blockIdx.y * TN;

  float acc[4][4] = {};

  for (int k0 = 0; k0 < Kd; k0 += TK) {
#pragma unroll
    for (int i = 0; i < 2; ++i) {
      const int r = (t >> 3) + i * 32;   // tile row 0..63
      const int c = (t & 7) * 4;         // k offset 0..28
      const float4 a = *reinterpret_cast<const float4*>(
          &X[(size_t)(bm + r) * Kd + k0 + c]);
      As[c + 0][r] = a.x; As[c + 1][r] = a.y;
      As[c + 2][r] = a.z; As[c + 3][r] = a.w;
      const float4 b = *reinterpret_cast<const float4*>(
          &W[(size_t)(bn + r) * Kd + k0 + c]);
      Bs[c + 0][r] = b.x; Bs[c + 1][r] = b.y;
      Bs[c + 2][r] = b.z; Bs[c + 3][r] = b.w;
    }
    __syncthreads();
#pragma unroll
    for (int kk = 0; kk < TK; ++kk) {
      const float4 av = *reinterpret_cast<const float4*>(&As[kk][ty * 4]);
      const float4 bv = *reinterpret_cast<const float4*>(&Bs[kk][tx * 4]);
      const float a_[4] = {av.x, av.y, av.z, av.w};
      const float b_[4] = {bv.x, bv.y, bv.z, bv.w};
#pragma unroll
      for (int ii = 0; ii < 4; ++ii)
#pragma unroll
        for (int jj = 0; jj < 4; ++jj)
          acc[ii][jj] += a_[ii] * b_[jj];
    }
    __syncthreads();
  }

  const int n = bn + tx * 4;
  const float4 bias4 = *reinterpret_cast<const float4*>(&bias[n]);
#pragma unroll
  for (int i = 0; i < 4; ++i) {
    const int m = bm + ty * 4 + i;
    float4 o;
    o.x = acc[i][0] + bias4.x;
    o.y = acc[i][1] + bias4.y;
    o.z = acc[i][2] + bias4.z;
    o.w = acc[i][3] + bias4.w;
    size_t idx;
    if (head_major) {
      const int b = m >> 10, s = m & (S_LEN - 1);
      const int h = n >> 6,  d = n & (HDIM - 1);
      idx = ((size_t)(b * NHEADS + h) * S_LEN + s) * HDIM + d;
    } else {
      idx = (size_t)m * DMODEL + n;
    }
    *reinterpret_cast<float4*>(&Y[idx]) = o;
  }
}

// ---------------------------------------------------------------------------
// Scores: e = exp((Q_bh @ K_bh^T) / 8), unnormalized, written to attn region.
// Per (b,h): M=N=1024, K=64 (single LDS stage). grid (16,16,128).
// ---------------------------------------------------------------------------
__global__ __launch_bounds__(256) void scores_exp_k(
    const float* __restrict__ Q, const float* __restrict__ Kmat,
    float* __restrict__ attn)
{
  __shared__ __align__(16) float Qs[HDIM][64 + 4];
  __shared__ __align__(16) float Ks[HDIM][64 + 4];
  const int t = threadIdx.x, tx = t & 15, ty = t >> 4;
  const int bm = blockIdx.x * 64, bn = blockIdx.y * 64;
  const int bh = blockIdx.z;
  const float* Qb = Q   + (size_t)bh * S_LEN * HDIM;
  const float* Kb = Kmat + (size_t)bh * S_LEN * HDIM;

#pragma unroll
  for (int i = 0; i < 4; ++i) {
    const int r = (t >> 4) + i * 16;   // tile row 0..63
    const int c = (t & 15) * 4;        // k offset 0..60
    const float4 q = *reinterpret_cast<const float4*>(
        &Qb[(size_t)(bm + r) * HDIM + c]);
    Qs[c + 0][r] = q.x; Qs[c + 1][r] = q.y;
    Qs[c + 2][r] = q.z; Qs[c + 3][r] = q.w;
    const float4 k = *reinterpret_cast<const float4*>(
        &Kb[(size_t)(bn + r) * HDIM + c]);
    Ks[c + 0][r] = k.x; Ks[c + 1][r] = k.y;
    Ks[c + 2][r] = k.z; Ks[c + 3][r] = k.w;
  }
  __syncthreads();

  float acc[4][4] = {};
#pragma unroll
  for (int kk = 0; kk < HDIM; ++kk) {
    const float4 av = *reinterpret_cast<const float4*>(&Qs[kk][ty * 4]);
    const float4 bv = *reinterpret_cast<const float4*>(&Ks[kk][tx * 4]);
    const float a_[4] = {av.x, av.y, av.z, av.w};
    const float b_[4] = {bv.x, bv.y, bv.z, bv.w};
#pragma unroll
    for (int ii = 0; ii < 4; ++ii)
#pragma unroll
      for (int jj = 0; jj < 4; ++jj)
        acc[ii][jj] += a_[ii] * b_[jj];
  }

  float* arow = attn + ((size_t)bh * S_LEN + bm + ty * 4) * S_LEN + bn + tx * 4;
#pragma unroll
  for (int i = 0; i < 4; ++i) {
    float4 e;
    e.x = expf(acc[i][0] * 0.125f);
    e.y = expf(acc[i][1] * 0.125f);
    e.z = expf(acc[i][2] * 0.125f);
    e.w = expf(acc[i][3] * 0.125f);
    *reinterpret_cast<float4*>(arow + (size_t)i * S_LEN) = e;
  }
}

// ---------------------------------------------------------------------------
// Row softmax normalization (in place). One block per row, deterministic
// block reduction (no float atomics). grid = 128*1024 blocks, 256 threads.
// ---------------------------------------------------------------------------
__global__ __launch_bounds__(256) void softmax_norm_k(float* __restrict__ attn)
{
  __shared__ float wsum[4];
  const size_t row = blockIdx.x;
  float4* p = reinterpret_cast<float4*>(attn + row * S_LEN);
  float4 v = p[threadIdx.x];
  float s = v.x + v.y + v.z + v.w;
#pragma unroll
  for (int off = 32; off > 0; off >>= 1) s += __shfl_xor(s, off, 64);
  const int lane = threadIdx.x & 63, wv = threadIdx.x >> 6;
  if (lane == 0) wsum[wv] = s;
  __syncthreads();
  const float inv = 1.0f / (wsum[0] + wsum[1] + wsum[2] + wsum[3]);
  v.x *= inv; v.y *= inv; v.z *= inv; v.w *= inv;
  p[threadIdx.x] = v;
}

// ---------------------------------------------------------------------------
// PV: ctx[b, s, h*64+d] = attn_bh @ V_bh.  M=1024, N=64, K=1024 per (b,h).
// V is already [k][n] so it stages into LDS without transpose.
// grid (16, 1, 128).
// ---------------------------------------------------------------------------
__global__ __launch_bounds__(256) void pv_k(
    const float* __restrict__ attn, const float* __restrict__ V,
    float* __restrict__ ctx)
{
  constexpr int TM = 64, TK = 32;
  __shared__ __align__(16) float As[TK][TM + 4];
  __shared__ __align__(16) float Bs[TK][HDIM + 4];
  const int t = threadIdx.x, tx = t & 15, ty = t >> 4;
  const int bm = blockIdx.x * TM;
  const int bh = blockIdx.z;
  const int b = bh >> 4, h = bh & 15;
  const float* Ab = attn + (size_t)bh * S_LEN * S_LEN;
  const float* Vb = V    + (size_t)bh * S_LEN * HDIM;

  float acc[4][4] = {};
  for (int k0 = 0; k0 < S_LEN; k0 += TK) {
#pragma unroll
    for (int i = 0; i < 2; ++i) {
      const int r = (t >> 3) + i * 32;   // attn tile row (m) 0..63
      const int c = (t & 7) * 4;         // k offset 0..28
      const float4 a = *reinterpret_cast<const float4*>(
          &Ab[(size_t)(bm + r) * S_LEN + k0 + c]);
      As[c + 0][r] = a.x; As[c + 1][r] = a.y;
      As[c + 2][r] = a.z; As[c + 3][r] = a.w;
      const int vr = (t >> 4) + i * 16;  // V tile row (k) 0..31
      const int vc = (t & 15) * 4;       // n 0..60
      *reinterpret_cast<float4*>(&Bs[vr][vc]) =
          *reinterpret_cast<const float4*>(&Vb[(size_t)(k0 + vr) * HDIM + vc]);
    }
    __syncthreads();
#pragma unroll
    for (int kk = 0; kk < TK; ++kk) {
      const float4 av = *reinterpret_cast<const float4*>(&As[kk][ty * 4]);
      const float4 bv = *reinterpret_cast<const float4*>(&Bs[kk][tx * 4]);
      const float a_[4] = {av.x, av.y, av.z, av.w};
      const float b_[4] = {bv.x, bv.y, bv.z, bv.w};
#pragma unroll
      for (int ii = 0; ii < 4; ++ii)
#pragma unroll
        for (int jj = 0; jj < 4; ++jj)
          acc[ii][jj] += a_[ii] * b_[jj];
    }
    __syncthreads();
  }

#pragma unroll
  for (int i = 0; i < 4; ++i) {
    const int s = bm + ty * 4 + i;
    const float4 o = make_float4(acc[i][0], acc[i][1], acc[i][2], acc[i][3]);
    *reinterpret_cast<float4*>(
        &ctx[(size_t)(b * S_LEN + s) * DMODEL + h * HDIM + tx * 4]) = o;
  }
}

// ---------------------------------------------------------------------------
extern "C" void kernel_launch(void* const* d_in, const int* in_sizes, int n_in,
                              void* d_out, int out_size, void* d_ws, size_t ws_size,
                              hipStream_t stream) {
  const float* query = (const float*)d_in[0];
  const float* key   = (const float*)d_in[1];
  const float* value = (const float*)d_in[2];
  const float* Wq    = (const float*)d_in[3];
  const float* bq    = (const float*)d_in[4];
  const float* Wk    = (const float*)d_in[5];
  const float* bk    = (const float*)d_in[6];
  const float* Wv    = (const float*)d_in[7];
  const float* bv    = (const float*)d_in[8];
  const float* Wo    = (const float*)d_in[9];
  const float* bo    = (const float*)d_in[10];

  float* out  = (float*)d_out;                       // [8192, 1024]
  float* attn = out + (size_t)MROWS * DMODEL;        // [128, 1024, 1024]

  float* Qw  = (float*)d_ws;                         // [128][1024][64]
  float* Kw  = Qw + (size_t)NBH * S_LEN * HDIM;
  float* Vw  = Kw + (size_t)NBH * S_LEN * HDIM;
  float* ctx = Qw;  // Q slab reused as context after scores are done

  const dim3 blk(256);
  const dim3 gproj(MROWS / 64, DMODEL / 64);         // (128, 16)

  proj_gemm_k<<<gproj, blk, 0, stream>>>(query, Wq, bq, Qw, 1);
  proj_gemm_k<<<gproj, blk, 0, stream>>>(key,   Wk, bk, Kw, 1);
  proj_gemm_k<<<gproj, blk, 0, stream>>>(value, Wv, bv, Vw, 1);

  const dim3 gsc(S_LEN / 64, S_LEN / 64, NBH);       // (16, 16, 128)
  scores_exp_k<<<gsc, blk, 0, stream>>>(Qw, Kw, attn);

  softmax_norm_k<<<dim3(NBH * S_LEN), blk, 0, stream>>>(attn);

  const dim3 gpv(S_LEN / 64, 1, NBH);                // (16, 1, 128)
  pv_k<<<gpv, blk, 0, stream>>>(attn, Vw, ctx);

  proj_gemm_k<<<gproj, blk, 0, stream>>>(ctx, Wo, bo, out, 0);
}

// Round 2
// 756.442 us; speedup vs baseline: 2.2451x; 2.2451x over previous
//
#include <hip/hip_runtime.h>
#include <cstddef>

typedef short s16x8 __attribute__((ext_vector_type(8)));
typedef short s16x4 __attribute__((ext_vector_type(4)));
typedef float f32x4 __attribute__((ext_vector_type(4)));

#define S_LEN 1024
#define NH 16
#define HD 64
#define NBH 128
#define MROWS 8192

__device__ __forceinline__ f32x4 mfma_bf16(s16x8 a, s16x8 b, f32x4 c) {
  return __builtin_amdgcn_mfma_f32_16x16x32_bf16(a, b, c, 0, 0, 0);
}

// truncation to bf16 (bit pattern = top 16)
__device__ __forceinline__ short bftr(float x) {
  return (short)(__float_as_uint(x) >> 16);
}
// split x = hi + lo (hi = truncated bf16, lo = bf16 of residual); |err| <= 2^-18 |x|
__device__ __forceinline__ void split1(float x, short& h, short& l) {
  const unsigned xu = __float_as_uint(x);
  h = (short)(xu >> 16);
  const float hf = __uint_as_float(xu & 0xffff0000u);
  l = (short)(__float_as_uint(x - hf) >> 16);
}

// ---------------------------------------------------------------------------
// fp32 -> bf16 hi/lo planes (for weights). grid*256*8 must equal n (1M).
// ---------------------------------------------------------------------------
__global__ __launch_bounds__(256) void convw_k(const float* __restrict__ W,
                                               short* __restrict__ hi,
                                               short* __restrict__ lo) {
  const int i = (blockIdx.x * 256 + threadIdx.x) * 8;
  float xs[8];
  *(float4*)&xs[0] = *(const float4*)&W[i];
  *(float4*)&xs[4] = *(const float4*)&W[i + 4];
  s16x8 H, L;
#pragma unroll
  for (int j = 0; j < 8; ++j) { short h, l; split1(xs[j], h, l); H[j] = h; L[j] = l; }
  *(s16x8*)&hi[i] = H;
  *(s16x8*)&lo[i] = L;
}

// ---------------------------------------------------------------------------
// Split-bf16 GEMM: Y = A @ W^T + bias,  A:[M,1024], W:[1024,1024] (both K-major)
// 3-term MFMA (hh + hl + lh) ~ fp32 accuracy. Tile 128x128, BK=32, 4 waves 2x2,
// wave = 64x64 = 4x4 frags of 16x16x32. LDS rows padded to 40 shorts (80 B)
// -> all ds_read_b128 / ds_write_b128 are 2 lanes/bank (free).
// MODE 0: out = hi/lo planes, head-major [(b*16+h)*1024+s]*64+d   (Q, K)
// MODE 1: out = plain bf16, per-head transposed [(bh*64+d)*1024+s] (V)
// MODE 2: out = fp32 [m][n]                                        (O)
// APRE: A is pre-split bf16 hi/lo planes (ctx) instead of fp32.
// ---------------------------------------------------------------------------
template <int MODE, bool APRE>
__global__ __launch_bounds__(256, 2) void proj_k(
    const float* __restrict__ Af, const short* __restrict__ Ahi,
    const short* __restrict__ Alo, const short* __restrict__ Whi,
    const short* __restrict__ Wlo, const float* __restrict__ bias,
    short* __restrict__ Ohi, short* __restrict__ Olo, float* __restrict__ Of) {
  __shared__ __align__(16) short Ah[128][40], Al[128][40];
  __shared__ __align__(16) short Bh[128][40], Bl[128][40];
  const int t = threadIdx.x;
  const int lane = t & 63, wid = t >> 6;
  const int wr = wid >> 1, wc = wid & 1;
  const int fr = lane & 15, fg = lane >> 4;
  const int bm = blockIdx.x * 128, bn = blockIdx.y * 128;
  const int srow = t >> 1, sk = (t & 1) * 16;

  f32x4 acc[4][4] = {};

  for (int k0 = 0; k0 < 1024; k0 += 32) {
    if constexpr (APRE) {
      const size_t ab = (size_t)(bm + srow) * 1024 + k0 + sk;
      const s16x8 h0 = *(const s16x8*)&Ahi[ab];
      const s16x8 h1 = *(const s16x8*)&Ahi[ab + 8];
      const s16x8 l0 = *(const s16x8*)&Alo[ab];
      const s16x8 l1 = *(const s16x8*)&Alo[ab + 8];
      *(s16x8*)&Ah[srow][sk] = h0; *(s16x8*)&Ah[srow][sk + 8] = h1;
      *(s16x8*)&Al[srow][sk] = l0; *(s16x8*)&Al[srow][sk + 8] = l1;
    } else {
      const float* ap = &Af[(size_t)(bm + srow) * 1024 + k0 + sk];
      float xs[16];
      *(float4*)&xs[0]  = *(const float4*)(ap);
      *(float4*)&xs[4]  = *(const float4*)(ap + 4);
      *(float4*)&xs[8]  = *(const float4*)(ap + 8);
      *(float4*)&xs[12] = *(const float4*)(ap + 12);
      s16x8 H0, L0, H1, L1;
#pragma unroll
      for (int j = 0; j < 8; ++j) { short h, l; split1(xs[j], h, l); H0[j] = h; L0[j] = l; }
#pragma unroll
      for (int j = 0; j < 8; ++j) { short h, l; split1(xs[8 + j], h, l); H1[j] = h; L1[j] = l; }
      *(s16x8*)&Ah[srow][sk] = H0; *(s16x8*)&Ah[srow][sk + 8] = H1;
      *(s16x8*)&Al[srow][sk] = L0; *(s16x8*)&Al[srow][sk + 8] = L1;
    }
    {
      const size_t wb = (size_t)(bn + srow) * 1024 + k0 + sk;
      const s16x8 h0 = *(const s16x8*)&Whi[wb];
      const s16x8 h1 = *(const s16x8*)&Whi[wb + 8];
      const s16x8 l0 = *(const s16x8*)&Wlo[wb];
      const s16x8 l1 = *(const s16x8*)&Wlo[wb + 8];
      *(s16x8*)&Bh[srow][sk] = h0; *(s16x8*)&Bh[srow][sk + 8] = h1;
      *(s16x8*)&Bl[srow][sk] = l0; *(s16x8*)&Bl[srow][sk + 8] = l1;
    }
    __syncthreads();
    s16x8 ah[4], al[4], bh[4], bl[4];
#pragma unroll
    for (int f = 0; f < 4; ++f) {
      ah[f] = *(const s16x8*)&Ah[wr * 64 + f * 16 + fr][fg * 8];
      al[f] = *(const s16x8*)&Al[wr * 64 + f * 16 + fr][fg * 8];
      bh[f] = *(const s16x8*)&Bh[wc * 64 + f * 16 + fr][fg * 8];
      bl[f] = *(const s16x8*)&Bl[wc * 64 + f * 16 + fr][fg * 8];
    }
#pragma unroll
    for (int i = 0; i < 4; ++i)
#pragma unroll
      for (int j = 0; j < 4; ++j) {
        acc[i][j] = mfma_bf16(ah[i], bh[j], acc[i][j]);
        acc[i][j] = mfma_bf16(ah[i], bl[j], acc[i][j]);
        acc[i][j] = mfma_bf16(al[i], bh[j], acc[i][j]);
      }
    __syncthreads();
  }

#pragma unroll
  for (int i = 0; i < 4; ++i) {
#pragma unroll
    for (int j = 0; j < 4; ++j) {
      const int m0 = bm + wr * 64 + i * 16 + fg * 4;
      const int n  = bn + wc * 64 + j * 16 + fr;
      const float bb = bias[n];
      if constexpr (MODE == 0) {
        const int batch = m0 >> 10, s0 = m0 & 1023;
        const int h = n >> 6, d = n & 63;
        const size_t base = ((size_t)(batch * NH + h) * S_LEN + s0) * HD + d;
#pragma unroll
        for (int r = 0; r < 4; ++r) {
          const float v = acc[i][j][r] + bb;
          short hh, ll; split1(v, hh, ll);
          Ohi[base + (size_t)r * HD] = hh;
          Olo[base + (size_t)r * HD] = ll;
        }
      } else if constexpr (MODE == 1) {
        const int batch = m0 >> 10, s0 = m0 & 1023;
        const int h = n >> 6, d = n & 63;
        s16x4 pk;
#pragma unroll
        for (int r = 0; r < 4; ++r) pk[r] = bftr(acc[i][j][r] + bb);
        *(s16x4*)&Ohi[((size_t)(batch * NH + h) * HD + d) * S_LEN + s0] = pk;
      } else {
#pragma unroll
        for (int r = 0; r < 4; ++r)
          Of[(size_t)(m0 + r) * 1024 + n] = acc[i][j][r] + bb;
      }
    }
  }
}

// ---------------------------------------------------------------------------
// Scores: per block = (b,h) x 64 q-rows. Loops 16 K-tiles: 3-term MFMA QK^T,
// exp(s/8) -> unnormalized attn (fp32), row sums in regs -> rinv = 1/sum.
// ---------------------------------------------------------------------------
__global__ __launch_bounds__(256) void scores_k(
    const short* __restrict__ Qhi, const short* __restrict__ Qlo,
    const short* __restrict__ Khi, const short* __restrict__ Klo,
    float* __restrict__ attn, float* __restrict__ rinv) {
  __shared__ __align__(16) short Kh[64][72], Kl[64][72];
  __shared__ float sums[2][64];
  const int t = threadIdx.x, lane = t & 63, wid = t >> 6;
  const int wq = wid >> 1, wk = wid & 1;
  const int fr = lane & 15, fg = lane >> 4;
  const int qb = blockIdx.x * 64, bh = blockIdx.y;
  const int srow = t >> 2, sc = (t & 3) * 16;

  s16x8 qh[2][2], ql[2][2];
#pragma unroll
  for (int fm = 0; fm < 2; ++fm)
#pragma unroll
    for (int kc = 0; kc < 2; ++kc) {
      const size_t qa =
          ((size_t)bh * S_LEN + qb + wq * 32 + fm * 16 + fr) * HD + kc * 32 + fg * 8;
      qh[fm][kc] = *(const s16x8*)&Qhi[qa];
      ql[fm][kc] = *(const s16x8*)&Qlo[qa];
    }

  float rs[2][4] = {};

  for (int kt = 0; kt < 16; ++kt) {
    const size_t kb = ((size_t)bh * S_LEN + kt * 64 + srow) * HD + sc;
    const s16x8 h0 = *(const s16x8*)&Khi[kb];
    const s16x8 h1 = *(const s16x8*)&Khi[kb + 8];
    const s16x8 l0 = *(const s16x8*)&Klo[kb];
    const s16x8 l1 = *(const s16x8*)&Klo[kb + 8];
    *(s16x8*)&Kh[srow][sc] = h0; *(s16x8*)&Kh[srow][sc + 8] = h1;
    *(s16x8*)&Kl[srow][sc] = l0; *(s16x8*)&Kl[srow][sc + 8] = l1;
    __syncthreads();

    s16x8 kh[2][2], kl[2][2];
#pragma unroll
    for (int fn = 0; fn < 2; ++fn)
#pragma unroll
      for (int kc = 0; kc < 2; ++kc) {
        kh[fn][kc] = *(const s16x8*)&Kh[wk * 32 + fn * 16 + fr][kc * 32 + fg * 8];
        kl[fn][kc] = *(const s16x8*)&Kl[wk * 32 + fn * 16 + fr][kc * 32 + fg * 8];
      }
    f32x4 s4[2][2] = {};
#pragma unroll
    for (int fm = 0; fm < 2; ++fm)
#pragma unroll
      for (int fn = 0; fn < 2; ++fn)
#pragma unroll
        for (int kc = 0; kc < 2; ++kc) {
          s4[fm][fn] = mfma_bf16(qh[fm][kc], kh[fn][kc], s4[fm][fn]);
          s4[fm][fn] = mfma_bf16(qh[fm][kc], kl[fn][kc], s4[fm][fn]);
          s4[fm][fn] = mfma_bf16(ql[fm][kc], kh[fn][kc], s4[fm][fn]);
        }
#pragma unroll
    for (int fm = 0; fm < 2; ++fm) {
      const size_t rbase =
          ((size_t)bh * S_LEN + qb + wq * 32 + fm * 16 + fg * 4) * S_LEN +
          kt * 64 + wk * 32 + fr;
#pragma unroll
      for (int fn = 0; fn < 2; ++fn)
#pragma unroll
        for (int r = 0; r < 4; ++r) {
          const float e = __expf(s4[fm][fn][r] * 0.125f);
          rs[fm][r] += e;
          attn[rbase + (size_t)r * S_LEN + fn * 16] = e;
        }
    }
    __syncthreads();
  }

#pragma unroll
  for (int fm = 0; fm < 2; ++fm)
#pragma unroll
    for (int r = 0; r < 4; ++r) {
      float v = rs[fm][r];
      v += __shfl_xor(v, 1); v += __shfl_xor(v, 2);
      v += __shfl_xor(v, 4); v += __shfl_xor(v, 8);
      rs[fm][r] = v;
    }
  if (fr == 0) {
#pragma unroll
    for (int fm = 0; fm < 2; ++fm)
#pragma unroll
      for (int r = 0; r < 4; ++r)
        sums[wk][wq * 32 + fm * 16 + fg * 4 + r] = rs[fm][r];
  }
  __syncthreads();
  if (t < 64) rinv[(size_t)bh * S_LEN + qb + t] = 1.0f / (sums[0][t] + sums[1][t]);
}

// ---------------------------------------------------------------------------
// PV + in-place normalize: per block = (b,h) x 64 q-rows. Loops 16 k-tiles:
// read exp tile, *rinv, write back (final attn output), bf16 -> MFMA with
// transposed V -> ctx written as hi/lo bf16 planes [8192][1024].
// ---------------------------------------------------------------------------
__global__ __launch_bounds__(256) void pv_k(
    float* __restrict__ attn, const short* __restrict__ Vt,
    const float* __restrict__ rinv, short* __restrict__ Chi,
    short* __restrict__ Clo) {
  __shared__ __align__(16) short At[64][72], Vs[64][72];
  const int t = threadIdx.x, lane = t & 63, wid = t >> 6;
  const int wq = wid >> 1, wd = wid & 1;
  const int fr = lane & 15, fg = lane >> 4;
  const int qb = blockIdx.x * 64, bh = blockIdx.y;
  const int batch = bh >> 4, h = bh & 15;
  const int srow = t >> 2, sc = (t & 3) * 16;
  const float inv = rinv[(size_t)bh * S_LEN + qb + srow];
  float* arow = attn + ((size_t)bh * S_LEN + qb + srow) * S_LEN + sc;
  const short* vrow = Vt + ((size_t)bh * HD + srow) * S_LEN + sc;

  f32x4 acc[2][2] = {};
  for (int kt = 0; kt < 16; ++kt) {
    float xs[16];
    *(float4*)&xs[0]  = *(const float4*)(arow + kt * 64);
    *(float4*)&xs[4]  = *(const float4*)(arow + kt * 64 + 4);
    *(float4*)&xs[8]  = *(const float4*)(arow + kt * 64 + 8);
    *(float4*)&xs[12] = *(const float4*)(arow + kt * 64 + 12);
#pragma unroll
    for (int j = 0; j < 16; ++j) xs[j] *= inv;
    s16x8 c0, c1;
#pragma unroll
    for (int j = 0; j < 8; ++j) { c0[j] = bftr(xs[j]); c1[j] = bftr(xs[8 + j]); }
    *(float4*)(arow + kt * 64)      = *(const float4*)&xs[0];
    *(float4*)(arow + kt * 64 + 4)  = *(const float4*)&xs[4];
    *(float4*)(arow + kt * 64 + 8)  = *(const float4*)&xs[8];
    *(float4*)(arow + kt * 64 + 12) = *(const float4*)&xs[12];
    const s16x8 v0 = *(const s16x8*)(vrow + kt * 64);
    const s16x8 v1 = *(const s16x8*)(vrow + kt * 64 + 8);
    *(s16x8*)&At[srow][sc] = c0; *(s16x8*)&At[srow][sc + 8] = c1;
    *(s16x8*)&Vs[srow][sc] = v0; *(s16x8*)&Vs[srow][sc + 8] = v1;
    __syncthreads();
    s16x8 af[2][2], bfv[2][2];
#pragma unroll
    for (int f = 0; f < 2; ++f)
#pragma unroll
      for (int kc = 0; kc < 2; ++kc) {
        af[f][kc]  = *(const s16x8*)&At[wq * 32 + f * 16 + fr][kc * 32 + fg * 8];
        bfv[f][kc] = *(const s16x8*)&Vs[wd * 32 + f * 16 + fr][kc * 32 + fg * 8];
      }
#pragma unroll
    for (int i = 0; i < 2; ++i)
#pragma unroll
      for (int j = 0; j < 2; ++j)
#pragma unroll
        for (int kc = 0; kc < 2; ++kc)
          acc[i][j] = mfma_bf16(af[i][kc], bfv[j][kc], acc[i][j]);
    __syncthreads();
  }

#pragma unroll
  for (int i = 0; i < 2; ++i)
#pragma unroll
    for (int j = 0; j < 2; ++j) {
      const int s0 = qb + wq * 32 + i * 16 + fg * 4;
      const int d = h * HD + wd * 32 + j * 16 + fr;
      const size_t base = ((size_t)batch * S_LEN + s0) * 1024 + d;
#pragma unroll
      for (int r = 0; r < 4; ++r) {
        short hh, ll; split1(acc[i][j][r], hh, ll);
        Chi[base + (size_t)r * 1024] = hh;
        Clo[base + (size_t)r * 1024] = ll;
      }
    }
}

// ---------------------------------------------------------------------------
extern "C" void kernel_launch(void* const* d_in, const int* in_sizes, int n_in,
                              void* d_out, int out_size, void* d_ws, size_t ws_size,
                              hipStream_t stream) {
  const float* query = (const float*)d_in[0];
  const float* key   = (const float*)d_in[1];
  const float* value = (const float*)d_in[2];
  const float* Wq    = (const float*)d_in[3];
  const float* bq    = (const float*)d_in[4];
  const float* Wk    = (const float*)d_in[5];
  const float* bk    = (const float*)d_in[6];
  const float* Wv    = (const float*)d_in[7];
  const float* bv    = (const float*)d_in[8];
  const float* Wo    = (const float*)d_in[9];
  const float* bo    = (const float*)d_in[10];

  float* out  = (float*)d_out;                  // [8192][1024]
  float* attn = out + (size_t)MROWS * 1024;     // [128][1024][1024]

  // ws layout (shorts): Q hi/lo, K hi/lo, Vt: 8388608 each; W hi/lo: 1048576
  short* qhi = (short*)d_ws;
  short* qlo = qhi + 8388608;
  short* khi = qlo + 8388608;
  short* klo = khi + 8388608;
  short* vt  = klo + 8388608;
  short* whi = vt  + 8388608;
  short* wlo = whi + 1048576;
  float* rinv = (float*)(wlo + 1048576);        // 128*1024 floats
  short* chi = qhi;  // ctx aliases Q planes (Q dead after scores_k)
  short* clo = qlo;

  const dim3 blk(256);
  const dim3 gp(64, 8);      // 128x128 tiles over 8192x1024
  const dim3 ga(16, NBH);    // 64 q-rows x (b,h)

  convw_k<<<512, blk, 0, stream>>>(Wq, whi, wlo);
  proj_k<0, false><<<gp, blk, 0, stream>>>(query, nullptr, nullptr, whi, wlo, bq,
                                           qhi, qlo, nullptr);
  convw_k<<<512, blk, 0, stream>>>(Wk, whi, wlo);
  proj_k<0, false><<<gp, blk, 0, stream>>>(key, nullptr, nullptr, whi, wlo, bk,
                                           khi, klo, nullptr);
  convw_k<<<512, blk, 0, stream>>>(Wv, whi, wlo);
  proj_k<1, false><<<gp, blk, 0, stream>>>(value, nullptr, nullptr, whi, wlo, bv,
                                           vt, nullptr, nullptr);

  scores_k<<<ga, blk, 0, stream>>>(qhi, qlo, khi, klo, attn, rinv);
  pv_k<<<ga, blk, 0, stream>>>(attn, vt, rinv, chi, clo);

  convw_k<<<512, blk, 0, stream>>>(Wo, whi, wlo);
  proj_k<2, true><<<gp, blk, 0, stream>>>(nullptr, chi, clo, whi, wlo, bo,
                                          nullptr, nullptr, out);
}

// Round 4
// 540.885 us; speedup vs baseline: 3.1398x; 1.3985x over previous
//
#include <hip/hip_runtime.h>
#include <cstddef>

typedef short s16x8 __attribute__((ext_vector_type(8)));
typedef short s16x4 __attribute__((ext_vector_type(4)));
typedef float f32x4 __attribute__((ext_vector_type(4)));

#define S_LEN 1024
#define NH 16
#define HD 64
#define NBH 128
#define MROWS 8192

__device__ __forceinline__ f32x4 mfma_bf16(s16x8 a, s16x8 b, f32x4 c) {
  return __builtin_amdgcn_mfma_f32_16x16x32_bf16(a, b, c, 0, 0, 0);
}

__device__ __forceinline__ short bftr(float x) {
  return (short)(__float_as_uint(x) >> 16);
}
// split x = hi + lo; |err| <= 2^-18 |x|
__device__ __forceinline__ void split1(float x, short& h, short& l) {
  const unsigned xu = __float_as_uint(x);
  h = (short)(xu >> 16);
  const float hf = __uint_as_float(xu & 0xffff0000u);
  l = (short)(__float_as_uint(x - hf) >> 16);
}

// ---------------------------------------------------------------------------
// fp32 -> bf16 hi/lo planes (weights). grid*256*8 == n.
// ---------------------------------------------------------------------------
__global__ __launch_bounds__(256) void convw_k(const float* __restrict__ W,
                                               short* __restrict__ hi,
                                               short* __restrict__ lo) {
  const int i = (blockIdx.x * 256 + threadIdx.x) * 8;
  float xs[8];
  *(float4*)&xs[0] = *(const float4*)&W[i];
  *(float4*)&xs[4] = *(const float4*)&W[i + 4];
  s16x8 H, L;
#pragma unroll
  for (int j = 0; j < 8; ++j) { short h, l; split1(xs[j], h, l); H[j] = h; L[j] = l; }
  *(s16x8*)&hi[i] = H;
  *(s16x8*)&lo[i] = L;
}

// ---------------------------------------------------------------------------
// Split-bf16 GEMM: Y = A @ W^T + bias (validated R2).
// MODE 0: hi/lo planes head-major (Q,K); MODE 1: bf16 transposed V; MODE 2: fp32.
// ---------------------------------------------------------------------------
template <int MODE, bool APRE>
__global__ __launch_bounds__(256, 2) void proj_k(
    const float* __restrict__ Af, const short* __restrict__ Ahi,
    const short* __restrict__ Alo, const short* __restrict__ Whi,
    const short* __restrict__ Wlo, const float* __restrict__ bias,
    short* __restrict__ Ohi, short* __restrict__ Olo, float* __restrict__ Of) {
  __shared__ __align__(16) short Ah[128][40], Al[128][40];
  __shared__ __align__(16) short Bh[128][40], Bl[128][40];
  const int t = threadIdx.x;
  const int lane = t & 63, wid = t >> 6;
  const int wr = wid >> 1, wc = wid & 1;
  const int fr = lane & 15, fg = lane >> 4;
  const int bm = blockIdx.x * 128, bn = blockIdx.y * 128;
  const int srow = t >> 1, sk = (t & 1) * 16;

  f32x4 acc[4][4] = {};

  for (int k0 = 0; k0 < 1024; k0 += 32) {
    if constexpr (APRE) {
      const size_t ab = (size_t)(bm + srow) * 1024 + k0 + sk;
      const s16x8 h0 = *(const s16x8*)&Ahi[ab];
      const s16x8 h1 = *(const s16x8*)&Ahi[ab + 8];
      const s16x8 l0 = *(const s16x8*)&Alo[ab];
      const s16x8 l1 = *(const s16x8*)&Alo[ab + 8];
      *(s16x8*)&Ah[srow][sk] = h0; *(s16x8*)&Ah[srow][sk + 8] = h1;
      *(s16x8*)&Al[srow][sk] = l0; *(s16x8*)&Al[srow][sk + 8] = l1;
    } else {
      const float* ap = &Af[(size_t)(bm + srow) * 1024 + k0 + sk];
      float xs[16];
      *(float4*)&xs[0]  = *(const float4*)(ap);
      *(float4*)&xs[4]  = *(const float4*)(ap + 4);
      *(float4*)&xs[8]  = *(const float4*)(ap + 8);
      *(float4*)&xs[12] = *(const float4*)(ap + 12);
      s16x8 H0, L0, H1, L1;
#pragma unroll
      for (int j = 0; j < 8; ++j) { short h, l; split1(xs[j], h, l); H0[j] = h; L0[j] = l; }
#pragma unroll
      for (int j = 0; j < 8; ++j) { short h, l; split1(xs[8 + j], h, l); H1[j] = h; L1[j] = l; }
      *(s16x8*)&Ah[srow][sk] = H0; *(s16x8*)&Ah[srow][sk + 8] = H1;
      *(s16x8*)&Al[srow][sk] = L0; *(s16x8*)&Al[srow][sk + 8] = L1;
    }
    {
      const size_t wb = (size_t)(bn + srow) * 1024 + k0 + sk;
      const s16x8 h0 = *(const s16x8*)&Whi[wb];
      const s16x8 h1 = *(const s16x8*)&Whi[wb + 8];
      const s16x8 l0 = *(const s16x8*)&Wlo[wb];
      const s16x8 l1 = *(const s16x8*)&Wlo[wb + 8];
      *(s16x8*)&Bh[srow][sk] = h0; *(s16x8*)&Bh[srow][sk + 8] = h1;
      *(s16x8*)&Bl[srow][sk] = l0; *(s16x8*)&Bl[srow][sk + 8] = l1;
    }
    __syncthreads();
    s16x8 ah[4], al[4], bh[4], bl[4];
#pragma unroll
    for (int f = 0; f < 4; ++f) {
      ah[f] = *(const s16x8*)&Ah[wr * 64 + f * 16 + fr][fg * 8];
      al[f] = *(const s16x8*)&Al[wr * 64 + f * 16 + fr][fg * 8];
      bh[f] = *(const s16x8*)&Bh[wc * 64 + f * 16 + fr][fg * 8];
      bl[f] = *(const s16x8*)&Bl[wc * 64 + f * 16 + fr][fg * 8];
    }
#pragma unroll
    for (int i = 0; i < 4; ++i)
#pragma unroll
      for (int j = 0; j < 4; ++j) {
        acc[i][j] = mfma_bf16(ah[i], bh[j], acc[i][j]);
        acc[i][j] = mfma_bf16(ah[i], bl[j], acc[i][j]);
        acc[i][j] = mfma_bf16(al[i], bh[j], acc[i][j]);
      }
    __syncthreads();
  }

#pragma unroll
  for (int i = 0; i < 4; ++i) {
#pragma unroll
    for (int j = 0; j < 4; ++j) {
      const int m0 = bm + wr * 64 + i * 16 + fg * 4;
      const int n  = bn + wc * 64 + j * 16 + fr;
      const float bb = bias[n];
      if constexpr (MODE == 0) {
        const int batch = m0 >> 10, s0 = m0 & 1023;
        const int h = n >> 6, d = n & 63;
        const size_t base = ((size_t)(batch * NH + h) * S_LEN + s0) * HD + d;
#pragma unroll
        for (int r = 0; r < 4; ++r) {
          const float v = acc[i][j][r] + bb;
          short hh, ll; split1(v, hh, ll);
          Ohi[base + (size_t)r * HD] = hh;
          Olo[base + (size_t)r * HD] = ll;
        }
      } else if constexpr (MODE == 1) {
        const int batch = m0 >> 10, s0 = m0 & 1023;
        const int h = n >> 6, d = n & 63;
        s16x4 pk;
#pragma unroll
        for (int r = 0; r < 4; ++r) pk[r] = bftr(acc[i][j][r] + bb);
        *(s16x4*)&Ohi[((size_t)(batch * NH + h) * HD + d) * S_LEN + s0] = pk;
      } else {
#pragma unroll
        for (int r = 0; r < 4; ++r)
          Of[(size_t)(m0 + r) * 1024 + n] = acc[i][j][r] + bb;
      }
    }
  }
}

// ---------------------------------------------------------------------------
// Attention: per block = (b,h) x 64 q-rows.
// Pass 1: 1-term (hi) QK^T -> exp -> row sums -> 1/sum (block-local).
// Pass 2: 3-term QK^T -> exp * rinv -> write normalized attn (final output).
// FUSE_PV=true additionally: P->bf16 via LDS transpose, MFMA with V tile ->
//   ctx hi/lo planes (MUST NOT alias Q/K/V — ctx gets its own slab).
// FUSE_PV=false: attn write only; PV runs as a separate kernel (pv2_k) whose
//   ctx may alias Q (cross-kernel, safe).
// ---------------------------------------------------------------------------
template <bool FUSE_PV>
__global__ __launch_bounds__(256) void attn_k(
    const short* __restrict__ Qhi, const short* __restrict__ Qlo,
    const short* __restrict__ Khi, const short* __restrict__ Klo,
    const short* __restrict__ Vt, float* __restrict__ attn,
    short* __restrict__ Chi, short* __restrict__ Clo) {
  __shared__ __align__(16) short Kh[64][72], Kl[64][72];
  __shared__ __align__(16) short Vs[FUSE_PV ? 64 : 1][72];
  __shared__ __align__(16) short Pt[FUSE_PV ? 64 : 1][72];
  __shared__ float sums[2][64];
  __shared__ float sinv[64];

  const int wg = blockIdx.x;                    // 2048 blocks, 2048%8==0
  const int w  = (wg & 7) * 256 + (wg >> 3);    // bijective XCD chunking
  const int bh = w >> 4;
  const int qb = (w & 15) * 64;
  const int batch = bh >> 4, h = bh & 15;

  const int t = threadIdx.x, lane = t & 63, wid = t >> 6;
  const int wq = wid >> 1, wk = wid & 1;
  const int fr = lane & 15, fg = lane >> 4;
  const int srow = t >> 2, sc = (t & 3) * 16;

  s16x8 qh[2][2], ql[2][2];
#pragma unroll
  for (int fm = 0; fm < 2; ++fm)
#pragma unroll
    for (int kc = 0; kc < 2; ++kc) {
      const size_t qa =
          ((size_t)bh * S_LEN + qb + wq * 32 + fm * 16 + fr) * HD + kc * 32 + fg * 8;
      qh[fm][kc] = *(const s16x8*)&Qhi[qa];
      ql[fm][kc] = *(const s16x8*)&Qlo[qa];
    }

  // ---------------- pass 1: cheap row sums ----------------
  float rs[2][4] = {};
  for (int kt = 0; kt < 16; ++kt) {
    const size_t kb = ((size_t)bh * S_LEN + kt * 64 + srow) * HD + sc;
    const s16x8 h0 = *(const s16x8*)&Khi[kb];
    const s16x8 h1 = *(const s16x8*)&Khi[kb + 8];
    *(s16x8*)&Kh[srow][sc] = h0; *(s16x8*)&Kh[srow][sc + 8] = h1;
    __syncthreads();
    s16x8 kh[2][2];
#pragma unroll
    for (int fn = 0; fn < 2; ++fn)
#pragma unroll
      for (int kc = 0; kc < 2; ++kc)
        kh[fn][kc] = *(const s16x8*)&Kh[wk * 32 + fn * 16 + fr][kc * 32 + fg * 8];
    f32x4 s4[2][2] = {};
#pragma unroll
    for (int fm = 0; fm < 2; ++fm)
#pragma unroll
      for (int fn = 0; fn < 2; ++fn)
#pragma unroll
        for (int kc = 0; kc < 2; ++kc)
          s4[fm][fn] = mfma_bf16(qh[fm][kc], kh[fn][kc], s4[fm][fn]);
#pragma unroll
    for (int fm = 0; fm < 2; ++fm)
#pragma unroll
      for (int fn = 0; fn < 2; ++fn)
#pragma unroll
        for (int r = 0; r < 4; ++r)
          rs[fm][r] += __expf(s4[fm][fn][r] * 0.125f);
    __syncthreads();
  }
#pragma unroll
  for (int fm = 0; fm < 2; ++fm)
#pragma unroll
    for (int r = 0; r < 4; ++r) {
      float v = rs[fm][r];
      v += __shfl_xor(v, 1); v += __shfl_xor(v, 2);
      v += __shfl_xor(v, 4); v += __shfl_xor(v, 8);
      rs[fm][r] = v;
    }
  if (fr == 0) {
#pragma unroll
    for (int fm = 0; fm < 2; ++fm)
#pragma unroll
      for (int r = 0; r < 4; ++r)
        sums[wk][wq * 32 + fm * 16 + fg * 4 + r] = rs[fm][r];
  }
  __syncthreads();
  if (t < 64) sinv[t] = 1.0f / (sums[0][t] + sums[1][t]);
  __syncthreads();

  float pinv[2][4];
#pragma unroll
  for (int fm = 0; fm < 2; ++fm)
#pragma unroll
    for (int r = 0; r < 4; ++r)
      pinv[fm][r] = sinv[wq * 32 + fm * 16 + fg * 4 + r];

  // ---------------- pass 2: exact scores + attn write (+ PV) ----------------
  f32x4 apv[2][2] = {};
  for (int kt = 0; kt < 16; ++kt) {
    {
      const size_t kb = ((size_t)bh * S_LEN + kt * 64 + srow) * HD + sc;
      const s16x8 h0 = *(const s16x8*)&Khi[kb];
      const s16x8 h1 = *(const s16x8*)&Khi[kb + 8];
      const s16x8 l0 = *(const s16x8*)&Klo[kb];
      const s16x8 l1 = *(const s16x8*)&Klo[kb + 8];
      *(s16x8*)&Kh[srow][sc] = h0; *(s16x8*)&Kh[srow][sc + 8] = h1;
      *(s16x8*)&Kl[srow][sc] = l0; *(s16x8*)&Kl[srow][sc + 8] = l1;
      if constexpr (FUSE_PV) {
        const short* vrow = Vt + ((size_t)bh * HD + srow) * S_LEN + kt * 64 + sc;
        const s16x8 v0 = *(const s16x8*)(vrow);
        const s16x8 v1 = *(const s16x8*)(vrow + 8);
        *(s16x8*)&Vs[srow][sc] = v0; *(s16x8*)&Vs[srow][sc + 8] = v1;
      }
    }
    __syncthreads();
    s16x8 kh[2][2], kl[2][2];
#pragma unroll
    for (int fn = 0; fn < 2; ++fn)
#pragma unroll
      for (int kc = 0; kc < 2; ++kc) {
        kh[fn][kc] = *(const s16x8*)&Kh[wk * 32 + fn * 16 + fr][kc * 32 + fg * 8];
        kl[fn][kc] = *(const s16x8*)&Kl[wk * 32 + fn * 16 + fr][kc * 32 + fg * 8];
      }
    f32x4 s4[2][2] = {};
#pragma unroll
    for (int fm = 0; fm < 2; ++fm)
#pragma unroll
      for (int fn = 0; fn < 2; ++fn)
#pragma unroll
        for (int kc = 0; kc < 2; ++kc) {
          s4[fm][fn] = mfma_bf16(qh[fm][kc], kh[fn][kc], s4[fm][fn]);
          s4[fm][fn] = mfma_bf16(qh[fm][kc], kl[fn][kc], s4[fm][fn]);
          s4[fm][fn] = mfma_bf16(ql[fm][kc], kh[fn][kc], s4[fm][fn]);
        }
#pragma unroll
    for (int fm = 0; fm < 2; ++fm) {
      const size_t rbase =
          ((size_t)bh * S_LEN + qb + wq * 32 + fm * 16 + fg * 4) * S_LEN +
          kt * 64 + wk * 32 + fr;
#pragma unroll
      for (int fn = 0; fn < 2; ++fn)
#pragma unroll
        for (int r = 0; r < 4; ++r) {
          const float e = __expf(s4[fm][fn][r] * 0.125f) * pinv[fm][r];
          attn[rbase + (size_t)r * S_LEN + fn * 16] = e;
          if constexpr (FUSE_PV)
            Pt[wq * 32 + fm * 16 + fg * 4 + r][wk * 32 + fn * 16 + fr] = bftr(e);
        }
    }
    __syncthreads();
    if constexpr (FUSE_PV) {
      s16x8 af[2][2], bv[2][2];
#pragma unroll
      for (int f = 0; f < 2; ++f)
#pragma unroll
        for (int kc = 0; kc < 2; ++kc) {
          af[f][kc] = *(const s16x8*)&Pt[wq * 32 + f * 16 + fr][kc * 32 + fg * 8];
          bv[f][kc] = *(const s16x8*)&Vs[wk * 32 + f * 16 + fr][kc * 32 + fg * 8];
        }
#pragma unroll
      for (int i = 0; i < 2; ++i)
#pragma unroll
        for (int j = 0; j < 2; ++j)
#pragma unroll
          for (int kc = 0; kc < 2; ++kc)
            apv[i][j] = mfma_bf16(af[i][kc], bv[j][kc], apv[i][j]);
      __syncthreads();
    }
  }

  if constexpr (FUSE_PV) {
#pragma unroll
    for (int i = 0; i < 2; ++i)
#pragma unroll
      for (int j = 0; j < 2; ++j) {
        const int s0 = qb + wq * 32 + i * 16 + fg * 4;
        const int d = h * HD + wk * 32 + j * 16 + fr;
        const size_t base = ((size_t)batch * S_LEN + s0) * 1024 + d;
#pragma unroll
        for (int r = 0; r < 4; ++r) {
          short hh, ll; split1(apv[i][j][r], hh, ll);
          Chi[base + (size_t)r * 1024] = hh;
          Clo[base + (size_t)r * 1024] = ll;
        }
      }
  }
}

// ---------------------------------------------------------------------------
// Fallback PV (split path): reads normalized attn, MFMA with V -> ctx planes.
// ctx may alias Q planes (cross-kernel; Q fully dead).
// ---------------------------------------------------------------------------
__global__ __launch_bounds__(256) void pv2_k(
    const float* __restrict__ attn, const short* __restrict__ Vt,
    short* __restrict__ Chi, short* __restrict__ Clo) {
  __shared__ __align__(16) short At[64][72], Vs[64][72];
  const int wg = blockIdx.x;
  const int w  = (wg & 7) * 256 + (wg >> 3);
  const int bh = w >> 4;
  const int qb = (w & 15) * 64;
  const int batch = bh >> 4, h = bh & 15;
  const int t = threadIdx.x, lane = t & 63, wid = t >> 6;
  const int wq = wid >> 1, wd = wid & 1;
  const int fr = lane & 15, fg = lane >> 4;
  const int srow = t >> 2, sc = (t & 3) * 16;
  const float* arow = attn + ((size_t)bh * S_LEN + qb + srow) * S_LEN + sc;
  const short* vrow = Vt + ((size_t)bh * HD + srow) * S_LEN + sc;

  f32x4 acc[2][2] = {};
  for (int kt = 0; kt < 16; ++kt) {
    float xs[16];
    *(float4*)&xs[0]  = *(const float4*)(arow + kt * 64);
    *(float4*)&xs[4]  = *(const float4*)(arow + kt * 64 + 4);
    *(float4*)&xs[8]  = *(const float4*)(arow + kt * 64 + 8);
    *(float4*)&xs[12] = *(const float4*)(arow + kt * 64 + 12);
    s16x8 c0, c1;
#pragma unroll
    for (int j = 0; j < 8; ++j) { c0[j] = bftr(xs[j]); c1[j] = bftr(xs[8 + j]); }
    const s16x8 v0 = *(const s16x8*)(vrow + kt * 64);
    const s16x8 v1 = *(const s16x8*)(vrow + kt * 64 + 8);
    *(s16x8*)&At[srow][sc] = c0; *(s16x8*)&At[srow][sc + 8] = c1;
    *(s16x8*)&Vs[srow][sc] = v0; *(s16x8*)&Vs[srow][sc + 8] = v1;
    __syncthreads();
    s16x8 af[2][2], bv[2][2];
#pragma unroll
    for (int f = 0; f < 2; ++f)
#pragma unroll
      for (int kc = 0; kc < 2; ++kc) {
        af[f][kc] = *(const s16x8*)&At[wq * 32 + f * 16 + fr][kc * 32 + fg * 8];
        bv[f][kc] = *(const s16x8*)&Vs[wd * 32 + f * 16 + fr][kc * 32 + fg * 8];
      }
#pragma unroll
    for (int i = 0; i < 2; ++i)
#pragma unroll
      for (int j = 0; j < 2; ++j)
#pragma unroll
        for (int kc = 0; kc < 2; ++kc)
          acc[i][j] = mfma_bf16(af[i][kc], bv[j][kc], acc[i][j]);
    __syncthreads();
  }

#pragma unroll
  for (int i = 0; i < 2; ++i)
#pragma unroll
    for (int j = 0; j < 2; ++j) {
      const int s0 = qb + wq * 32 + i * 16 + fg * 4;
      const int d = h * HD + wd * 32 + j * 16 + fr;
      const size_t base = ((size_t)batch * S_LEN + s0) * 1024 + d;
#pragma unroll
      for (int r = 0; r < 4; ++r) {
        short hh, ll; split1(acc[i][j][r], hh, ll);
        Chi[base + (size_t)r * 1024] = hh;
        Clo[base + (size_t)r * 1024] = ll;
      }
    }
}

// ---------------------------------------------------------------------------
extern "C" void kernel_launch(void* const* d_in, const int* in_sizes, int n_in,
                              void* d_out, int out_size, void* d_ws, size_t ws_size,
                              hipStream_t stream) {
  const float* query = (const float*)d_in[0];
  const float* key   = (const float*)d_in[1];
  const float* value = (const float*)d_in[2];
  const float* Wq    = (const float*)d_in[3];
  const float* bq    = (const float*)d_in[4];
  const float* Wk    = (const float*)d_in[5];
  const float* bk    = (const float*)d_in[6];
  const float* Wv    = (const float*)d_in[7];
  const float* bv    = (const float*)d_in[8];
  const float* Wo    = (const float*)d_in[9];
  const float* bo    = (const float*)d_in[10];

  float* out  = (float*)d_out;                  // [8192][1024]
  float* attn = out + (size_t)MROWS * 1024;     // [128][1024][1024]

  short* qhi = (short*)d_ws;
  short* qlo = qhi + 8388608;
  short* khi = qlo + 8388608;
  short* klo = khi + 8388608;
  short* vt  = klo + 8388608;
  short* whi = vt  + 8388608;
  short* wlo = whi + 1048576;
  short* cxh = wlo + 1048576;   // fused path only: fresh 32MB, no alias
  short* cxl = cxh + 8388608;

  // bytes needed for the fused path (7 full planes + 2 weight planes)
  const size_t need_fused = ((size_t)7 * 8388608 + 2 * 1048576) * sizeof(short);
  const bool fuse = ws_size >= need_fused;

  const dim3 blk(256);
  const dim3 gp(64, 8);

  convw_k<<<512, blk, 0, stream>>>(Wq, whi, wlo);
  proj_k<0, false><<<gp, blk, 0, stream>>>(query, nullptr, nullptr, whi, wlo, bq,
                                           qhi, qlo, nullptr);
  convw_k<<<512, blk, 0, stream>>>(Wk, whi, wlo);
  proj_k<0, false><<<gp, blk, 0, stream>>>(key, nullptr, nullptr, whi, wlo, bk,
                                           khi, klo, nullptr);
  convw_k<<<512, blk, 0, stream>>>(Wv, whi, wlo);
  proj_k<1, false><<<gp, blk, 0, stream>>>(value, nullptr, nullptr, whi, wlo, bv,
                                           vt, nullptr, nullptr);

  short *chFinal, *clFinal;
  if (fuse) {
    attn_k<true><<<dim3(2048), blk, 0, stream>>>(qhi, qlo, khi, klo, vt, attn,
                                                 cxh, cxl);
    chFinal = cxh; clFinal = cxl;
  } else {
    attn_k<false><<<dim3(2048), blk, 0, stream>>>(qhi, qlo, khi, klo, vt, attn,
                                                  nullptr, nullptr);
    // ctx aliases Q planes — safe across kernel boundary (Q dead now)
    pv2_k<<<dim3(2048), blk, 0, stream>>>(attn, vt, qhi, qlo);
    chFinal = qhi; clFinal = qlo;
  }

  convw_k<<<512, blk, 0, stream>>>(Wo, whi, wlo);
  proj_k<2, true><<<gp, blk, 0, stream>>>(nullptr, chFinal, clFinal, whi, wlo, bo,
                                          nullptr, nullptr, out);
}

// Round 5
// 513.308 us; speedup vs baseline: 3.3085x; 1.0537x over previous
//
#include <hip/hip_runtime.h>
#include <cstddef>
#include <cstdint>

typedef short s16x8 __attribute__((ext_vector_type(8)));
typedef short s16x4 __attribute__((ext_vector_type(4)));
typedef float f32x4 __attribute__((ext_vector_type(4)));

#define S_LEN 1024
#define NH 16
#define HD 64
#define NBH 128
#define MROWS 8192

__device__ __forceinline__ f32x4 mfma_bf16(s16x8 a, s16x8 b, f32x4 c) {
  return __builtin_amdgcn_mfma_f32_16x16x32_bf16(a, b, c, 0, 0, 0);
}
__device__ __forceinline__ short bftr(float x) {
  return (short)(__float_as_uint(x) >> 16);
}
// split x = hi + lo; |err| <= 2^-18 |x|
__device__ __forceinline__ void split1(float x, short& h, short& l) {
  const unsigned xu = __float_as_uint(x);
  h = (short)(xu >> 16);
  const float hf = __uint_as_float(xu & 0xffff0000u);
  l = (short)(__float_as_uint(x - hf) >> 16);
}

// async global->LDS DMA, 16B/lane: HW writes lane i at ldsbase + i*16.
// ldsbase must be wave-uniform; gptr is per-lane.
typedef const __attribute__((address_space(1))) unsigned int* as1_u32p;
typedef __attribute__((address_space(3))) unsigned int* as3_u32p;
__device__ __forceinline__ void gl_lds16(const short* g, short* l) {
  __builtin_amdgcn_global_load_lds((as1_u32p)(const void*)g,
                                   (as3_u32p)(void*)l, 16, 0, 0);
}

// ---------------------------------------------------------------------------
// fp32 -> bf16 hi/lo planes in K-STEP-TILED order:
//   dst = ((nb*32 + ks)*128 + row)*32 + k   (nb=n>>7, row=n&127, ks/k of kdim)
// so each 128x32 B-tile is a contiguous 8KB slab for global_load_lds.
// ---------------------------------------------------------------------------
__global__ __launch_bounds__(256) void convw_k(const float* __restrict__ W,
                                               short* __restrict__ hi,
                                               short* __restrict__ lo) {
  const int i = (blockIdx.x * 256 + threadIdx.x) * 8;
  const int n = i >> 10, kg = i & 1023;
  const int dst = (((n >> 7) * 32 + (kg >> 5)) * 128 + (n & 127)) * 32 + (kg & 31);
  float xs[8];
  *(float4*)&xs[0] = *(const float4*)&W[i];
  *(float4*)&xs[4] = *(const float4*)&W[i + 4];
  s16x8 H, L;
#pragma unroll
  for (int j = 0; j < 8; ++j) { short h, l; split1(xs[j], h, l); H[j] = h; L[j] = l; }
  *(s16x8*)&hi[dst] = H;
  *(s16x8*)&lo[dst] = L;
}

// ---------------------------------------------------------------------------
// Split-bf16 GEMM: Y = A @ W^T + bias. B staged via global_load_lds from
// tiled planes into linear [128][32] LDS (conflict-free b128 frag reads).
// APRE: A also DMA'd from tiled planes. !APRE: A fp32, reg-split into padded
// [128][40]. 3-term MFMA (hh+hl+lh). XCD-chunked 1-D grid (512 blocks).
// MODE 0: hi/lo planes head-major (Q,K); MODE 1: bf16 V^T; MODE 2: fp32 out.
// ---------------------------------------------------------------------------
template <int MODE, bool APRE>
__global__ __launch_bounds__(256, 2) void proj_k(
    const float* __restrict__ Af, const short* __restrict__ Ahi,
    const short* __restrict__ Alo, const short* __restrict__ Whi,
    const short* __restrict__ Wlo, const float* __restrict__ bias,
    short* __restrict__ Ohi, short* __restrict__ Olo, float* __restrict__ Of) {
  constexpr int AW = APRE ? 32 : 40;
  __shared__ __align__(16) short Ah[128][AW], Al[128][AW];
  __shared__ __align__(16) short Bh[128][32], Bl[128][32];
  const int t = threadIdx.x, lane = t & 63, wid = t >> 6;
  const int wr = wid >> 1, wc = wid & 1;
  const int fr = lane & 15, fg = lane >> 4;
  const int bid = blockIdx.x;                 // 512 blocks, 512%8==0
  const int wg = (bid & 7) * 64 + (bid >> 3); // XCD chunk, M-major
  const int bm = (wg >> 3) * 128, bn = (wg & 7) * 128;
  const int srow = t >> 1, sk = (t & 1) * 16;

  f32x4 acc[4][4] = {};

  for (int ks = 0; ks < 32; ++ks) {
    const int k0 = ks * 32;
    {  // B: DMA hi+lo (8KB each): wave w stages 1KB chunks {2w, 2w+1}
      const size_t boff = ((size_t)(bn >> 7) * 32 + ks) * 4096;
      const int c0 = wid * 2;
      gl_lds16(&Whi[boff + (size_t)c0 * 512 + lane * 8],       &Bh[0][0] + c0 * 512);
      gl_lds16(&Whi[boff + (size_t)(c0 + 1) * 512 + lane * 8], &Bh[0][0] + (c0 + 1) * 512);
      gl_lds16(&Wlo[boff + (size_t)c0 * 512 + lane * 8],       &Bl[0][0] + c0 * 512);
      gl_lds16(&Wlo[boff + (size_t)(c0 + 1) * 512 + lane * 8], &Bl[0][0] + (c0 + 1) * 512);
    }
    if constexpr (APRE) {
      const size_t aoff = ((size_t)(bm >> 7) * 32 + ks) * 4096;
      const int c0 = wid * 2;
      gl_lds16(&Ahi[aoff + (size_t)c0 * 512 + lane * 8],       &Ah[0][0] + c0 * 512);
      gl_lds16(&Ahi[aoff + (size_t)(c0 + 1) * 512 + lane * 8], &Ah[0][0] + (c0 + 1) * 512);
      gl_lds16(&Alo[aoff + (size_t)c0 * 512 + lane * 8],       &Al[0][0] + c0 * 512);
      gl_lds16(&Alo[aoff + (size_t)(c0 + 1) * 512 + lane * 8], &Al[0][0] + (c0 + 1) * 512);
    } else {
      const float* ap = &Af[(size_t)(bm + srow) * 1024 + k0 + sk];
      float xs[16];
      *(float4*)&xs[0]  = *(const float4*)(ap);
      *(float4*)&xs[4]  = *(const float4*)(ap + 4);
      *(float4*)&xs[8]  = *(const float4*)(ap + 8);
      *(float4*)&xs[12] = *(const float4*)(ap + 12);
      s16x8 H0, L0, H1, L1;
#pragma unroll
      for (int j = 0; j < 8; ++j) { short h, l; split1(xs[j], h, l); H0[j] = h; L0[j] = l; }
#pragma unroll
      for (int j = 0; j < 8; ++j) { short h, l; split1(xs[8 + j], h, l); H1[j] = h; L1[j] = l; }
      *(s16x8*)&Ah[srow][sk] = H0; *(s16x8*)&Ah[srow][sk + 8] = H1;
      *(s16x8*)&Al[srow][sk] = L0; *(s16x8*)&Al[srow][sk + 8] = L1;
    }
    __syncthreads();
    s16x8 ah[4], al[4], bh[4], bl[4];
#pragma unroll
    for (int f = 0; f < 4; ++f) {
      ah[f] = *(const s16x8*)&Ah[wr * 64 + f * 16 + fr][fg * 8];
      al[f] = *(const s16x8*)&Al[wr * 64 + f * 16 + fr][fg * 8];
      bh[f] = *(const s16x8*)&Bh[wc * 64 + f * 16 + fr][fg * 8];
      bl[f] = *(const s16x8*)&Bl[wc * 64 + f * 16 + fr][fg * 8];
    }
#pragma unroll
    for (int i = 0; i < 4; ++i)
#pragma unroll
      for (int j = 0; j < 4; ++j) {
        acc[i][j] = mfma_bf16(ah[i], bh[j], acc[i][j]);
        acc[i][j] = mfma_bf16(ah[i], bl[j], acc[i][j]);
        acc[i][j] = mfma_bf16(al[i], bh[j], acc[i][j]);
      }
    __syncthreads();
  }

#pragma unroll
  for (int i = 0; i < 4; ++i) {
#pragma unroll
    for (int j = 0; j < 4; ++j) {
      const int m0 = bm + wr * 64 + i * 16 + fg * 4;
      const int n  = bn + wc * 64 + j * 16 + fr;
      const float bb = bias[n];
      if constexpr (MODE == 0) {
        const int batch = m0 >> 10, s0 = m0 & 1023;
        const int h = n >> 6, d = n & 63;
        const size_t base = ((size_t)(batch * NH + h) * S_LEN + s0) * HD + d;
#pragma unroll
        for (int r = 0; r < 4; ++r) {
          const float v = acc[i][j][r] + bb;
          short hh, ll; split1(v, hh, ll);
          Ohi[base + (size_t)r * HD] = hh;
          Olo[base + (size_t)r * HD] = ll;
        }
      } else if constexpr (MODE == 1) {
        const int batch = m0 >> 10, s0 = m0 & 1023;
        const int h = n >> 6, d = n & 63;
        s16x4 pk;
#pragma unroll
        for (int r = 0; r < 4; ++r) pk[r] = bftr(acc[i][j][r] + bb);
        *(s16x4*)&Ohi[((size_t)(batch * NH + h) * HD + d) * S_LEN + s0] = pk;
      } else {
#pragma unroll
        for (int r = 0; r < 4; ++r)
          Of[(size_t)(m0 + r) * 1024 + n] = acc[i][j][r] + bb;
      }
    }
  }
}

// ---------------------------------------------------------------------------
// Attention, transposed-score variant: s^T = mfma(K, Q) so each lane holds 4
// CONSECUTIVE k for fixed q -> float4 attn stores, b64 Pt writes.
// Pass 1: 1-term QK^T -> exp -> row sums -> 1/sum.
// Pass 2: 3-term -> exp*rinv -> attn (final, float4) [+ PV -> ctx tiled planes].
// ---------------------------------------------------------------------------
template <bool FUSE_PV>
__global__ __launch_bounds__(256) void attn_k(
    const short* __restrict__ Qhi, const short* __restrict__ Qlo,
    const short* __restrict__ Khi, const short* __restrict__ Klo,
    const short* __restrict__ Vt, float* __restrict__ attn,
    short* __restrict__ Chi, short* __restrict__ Clo) {
  __shared__ __align__(16) short Kh[64][72], Kl[64][72];
  __shared__ __align__(16) short Vs[FUSE_PV ? 64 : 1][72];
  __shared__ __align__(16) short Pt[FUSE_PV ? 64 : 1][72];
  __shared__ float sums[2][64];
  __shared__ float sinv[64];

  const int wg = blockIdx.x;                    // 2048 blocks, 2048%8==0
  const int w  = (wg & 7) * 256 + (wg >> 3);    // bijective XCD chunking
  const int bh = w >> 4;
  const int qb = (w & 15) * 64;
  const int batch = bh >> 4, h = bh & 15;

  const int t = threadIdx.x, lane = t & 63, wid = t >> 6;
  const int wq = wid >> 1, wk = wid & 1;
  const int fr = lane & 15, fg = lane >> 4;
  const int srow = t >> 2, sc = (t & 3) * 16;

  s16x8 qh[2][2], ql[2][2];
#pragma unroll
  for (int fm = 0; fm < 2; ++fm)
#pragma unroll
    for (int kc = 0; kc < 2; ++kc) {
      const size_t qa =
          ((size_t)bh * S_LEN + qb + wq * 32 + fm * 16 + fr) * HD + kc * 32 + fg * 8;
      qh[fm][kc] = *(const s16x8*)&Qhi[qa];
      ql[fm][kc] = *(const s16x8*)&Qlo[qa];
    }

  // ---------------- pass 1: cheap row sums ----------------
  float rs[2] = {};
  for (int kt = 0; kt < 16; ++kt) {
    const size_t kb = ((size_t)bh * S_LEN + kt * 64 + srow) * HD + sc;
    const s16x8 h0 = *(const s16x8*)&Khi[kb];
    const s16x8 h1 = *(const s16x8*)&Khi[kb + 8];
    *(s16x8*)&Kh[srow][sc] = h0; *(s16x8*)&Kh[srow][sc + 8] = h1;
    __syncthreads();
    s16x8 kh[2][2];
#pragma unroll
    for (int fn = 0; fn < 2; ++fn)
#pragma unroll
      for (int kc = 0; kc < 2; ++kc)
        kh[fn][kc] = *(const s16x8*)&Kh[wk * 32 + fn * 16 + fr][kc * 32 + fg * 8];
    f32x4 s4[2][2] = {};  // [fn][fm]: D rows = k, cols = q
#pragma unroll
    for (int fn = 0; fn < 2; ++fn)
#pragma unroll
      for (int fm = 0; fm < 2; ++fm)
#pragma unroll
        for (int kc = 0; kc < 2; ++kc)
          s4[fn][fm] = mfma_bf16(kh[fn][kc], qh[fm][kc], s4[fn][fm]);
#pragma unroll
    for (int fn = 0; fn < 2; ++fn)
#pragma unroll
      for (int fm = 0; fm < 2; ++fm)
#pragma unroll
        for (int r = 0; r < 4; ++r)
          rs[fm] += __expf(s4[fn][fm][r] * 0.125f);
    __syncthreads();
  }
#pragma unroll
  for (int fm = 0; fm < 2; ++fm) {
    float v = rs[fm];
    v += __shfl_xor(v, 16); v += __shfl_xor(v, 32);   // sum across fg
    if (fg == 0) sums[wk][wq * 32 + fm * 16 + fr] = v;
  }
  __syncthreads();
  if (t < 64) sinv[t] = 1.0f / (sums[0][t] + sums[1][t]);
  __syncthreads();

  float pinv[2];
#pragma unroll
  for (int fm = 0; fm < 2; ++fm) pinv[fm] = sinv[wq * 32 + fm * 16 + fr];

  // ---------------- pass 2: exact scores + attn write (+ PV) ----------------
  f32x4 apv[2][2] = {};
  for (int kt = 0; kt < 16; ++kt) {
    {
      const size_t kb = ((size_t)bh * S_LEN + kt * 64 + srow) * HD + sc;
      const s16x8 h0 = *(const s16x8*)&Khi[kb];
      const s16x8 h1 = *(const s16x8*)&Khi[kb + 8];
      const s16x8 l0 = *(const s16x8*)&Klo[kb];
      const s16x8 l1 = *(const s16x8*)&Klo[kb + 8];
      *(s16x8*)&Kh[srow][sc] = h0; *(s16x8*)&Kh[srow][sc + 8] = h1;
      *(s16x8*)&Kl[srow][sc] = l0; *(s16x8*)&Kl[srow][sc + 8] = l1;
      if constexpr (FUSE_PV) {
        const short* vrow = Vt + ((size_t)bh * HD + srow) * S_LEN + kt * 64 + sc;
        const s16x8 v0 = *(const s16x8*)(vrow);
        const s16x8 v1 = *(const s16x8*)(vrow + 8);
        *(s16x8*)&Vs[srow][sc] = v0; *(s16x8*)&Vs[srow][sc + 8] = v1;
      }
    }
    __syncthreads();
    s16x8 kh[2][2], kl[2][2];
#pragma unroll
    for (int fn = 0; fn < 2; ++fn)
#pragma unroll
      for (int kc = 0; kc < 2; ++kc) {
        kh[fn][kc] = *(const s16x8*)&Kh[wk * 32 + fn * 16 + fr][kc * 32 + fg * 8];
        kl[fn][kc] = *(const s16x8*)&Kl[wk * 32 + fn * 16 + fr][kc * 32 + fg * 8];
      }
    f32x4 s4[2][2] = {};  // [fn][fm]
#pragma unroll
    for (int fn = 0; fn < 2; ++fn)
#pragma unroll
      for (int fm = 0; fm < 2; ++fm)
#pragma unroll
        for (int kc = 0; kc < 2; ++kc) {
          s4[fn][fm] = mfma_bf16(kh[fn][kc], qh[fm][kc], s4[fn][fm]);
          s4[fn][fm] = mfma_bf16(kh[fn][kc], ql[fm][kc], s4[fn][fm]);
          s4[fn][fm] = mfma_bf16(kl[fn][kc], qh[fm][kc], s4[fn][fm]);
        }
#pragma unroll
    for (int fm = 0; fm < 2; ++fm) {
      const int q = qb + wq * 32 + fm * 16 + fr;
#pragma unroll
      for (int fn = 0; fn < 2; ++fn) {
        const int kbase = wk * 32 + fn * 16 + fg * 4;  // k within 64-tile
        float4 e4;
        e4.x = __expf(s4[fn][fm][0] * 0.125f) * pinv[fm];
        e4.y = __expf(s4[fn][fm][1] * 0.125f) * pinv[fm];
        e4.z = __expf(s4[fn][fm][2] * 0.125f) * pinv[fm];
        e4.w = __expf(s4[fn][fm][3] * 0.125f) * pinv[fm];
        *(float4*)&attn[((size_t)bh * S_LEN + q) * S_LEN + kt * 64 + kbase] = e4;
        if constexpr (FUSE_PV) {
          s16x4 pk;
          pk[0] = bftr(e4.x); pk[1] = bftr(e4.y);
          pk[2] = bftr(e4.z); pk[3] = bftr(e4.w);
          *(s16x4*)&Pt[wq * 32 + fm * 16 + fr][kbase] = pk;
        }
      }
    }
    __syncthreads();
    if constexpr (FUSE_PV) {
      s16x8 af[2][2], bv[2][2];
#pragma unroll
      for (int f = 0; f < 2; ++f)
#pragma unroll
        for (int kc = 0; kc < 2; ++kc) {
          af[f][kc] = *(const s16x8*)&Pt[wq * 32 + f * 16 + fr][kc * 32 + fg * 8];
          bv[f][kc] = *(const s16x8*)&Vs[wk * 32 + f * 16 + fr][kc * 32 + fg * 8];
        }
#pragma unroll
      for (int i = 0; i < 2; ++i)
#pragma unroll
        for (int j = 0; j < 2; ++j)
#pragma unroll
          for (int kc = 0; kc < 2; ++kc)
            apv[i][j] = mfma_bf16(af[i][kc], bv[j][kc], apv[i][j]);
      __syncthreads();
    }
  }

  if constexpr (FUSE_PV) {
    // ctx -> hi/lo planes in K-STEP-TILED order for the O-proj DMA
#pragma unroll
    for (int i = 0; i < 2; ++i)
#pragma unroll
      for (int j = 0; j < 2; ++j) {
        const int s0 = qb + wq * 32 + i * 16 + fg * 4;
        const int d = h * HD + wk * 32 + j * 16 + fr;
#pragma unroll
        for (int r = 0; r < 4; ++r) {
          const int m = batch * S_LEN + s0 + r;
          const size_t idx =
              (((size_t)(m >> 7) * 32 + (d >> 5)) * 128 + (m & 127)) * 32 + (d & 31);
          short hh, ll; split1(apv[i][j][r], hh, ll);
          Chi[idx] = hh;
          Clo[idx] = ll;
        }
      }
  }
}

// ---------------------------------------------------------------------------
// Fallback PV (split path): reads normalized attn, MFMA with V -> ctx tiled
// planes. ctx may alias Q planes (cross-kernel; Q fully dead).
// ---------------------------------------------------------------------------
__global__ __launch_bounds__(256) void pv2_k(
    const float* __restrict__ attn, const short* __restrict__ Vt,
    short* __restrict__ Chi, short* __restrict__ Clo) {
  __shared__ __align__(16) short At[64][72], Vs[64][72];
  const int wg = blockIdx.x;
  const int w  = (wg & 7) * 256 + (wg >> 3);
  const int bh = w >> 4;
  const int qb = (w & 15) * 64;
  const int batch = bh >> 4, h = bh & 15;
  const int t = threadIdx.x, lane = t & 63, wid = t >> 6;
  const int wq = wid >> 1, wd = wid & 1;
  const int fr = lane & 15, fg = lane >> 4;
  const int srow = t >> 2, sc = (t & 3) * 16;
  const float* arow = attn + ((size_t)bh * S_LEN + qb + srow) * S_LEN + sc;
  const short* vrow = Vt + ((size_t)bh * HD + srow) * S_LEN + sc;

  f32x4 acc[2][2] = {};
  for (int kt = 0; kt < 16; ++kt) {
    float xs[16];
    *(float4*)&xs[0]  = *(const float4*)(arow + kt * 64);
    *(float4*)&xs[4]  = *(const float4*)(arow + kt * 64 + 4);
    *(float4*)&xs[8]  = *(const float4*)(arow + kt * 64 + 8);
    *(float4*)&xs[12] = *(const float4*)(arow + kt * 64 + 12);
    s16x8 c0, c1;
#pragma unroll
    for (int j = 0; j < 8; ++j) { c0[j] = bftr(xs[j]); c1[j] = bftr(xs[8 + j]); }
    const s16x8 v0 = *(const s16x8*)(vrow + kt * 64);
    const s16x8 v1 = *(const s16x8*)(vrow + kt * 64 + 8);
    *(s16x8*)&At[srow][sc] = c0; *(s16x8*)&At[srow][sc + 8] = c1;
    *(s16x8*)&Vs[srow][sc] = v0; *(s16x8*)&Vs[srow][sc + 8] = v1;
    __syncthreads();
    s16x8 af[2][2], bv[2][2];
#pragma unroll
    for (int f = 0; f < 2; ++f)
#pragma unroll
      for (int kc = 0; kc < 2; ++kc) {
        af[f][kc] = *(const s16x8*)&At[wq * 32 + f * 16 + fr][kc * 32 + fg * 8];
        bv[f][kc] = *(const s16x8*)&Vs[wd * 32 + f * 16 + fr][kc * 32 + fg * 8];
      }
#pragma unroll
    for (int i = 0; i < 2; ++i)
#pragma unroll
      for (int j = 0; j < 2; ++j)
#pragma unroll
        for (int kc = 0; kc < 2; ++kc)
          acc[i][j] = mfma_bf16(af[i][kc], bv[j][kc], acc[i][j]);
    __syncthreads();
  }

#pragma unroll
  for (int i = 0; i < 2; ++i)
#pragma unroll
    for (int j = 0; j < 2; ++j) {
      const int s0 = qb + wq * 32 + i * 16 + fg * 4;
      const int d = h * HD + wd * 32 + j * 16 + fr;
#pragma unroll
      for (int r = 0; r < 4; ++r) {
        const int m = batch * S_LEN + s0 + r;
        const size_t idx =
            (((size_t)(m >> 7) * 32 + (d >> 5)) * 128 + (m & 127)) * 32 + (d & 31);
        short hh, ll; split1(acc[i][j][r], hh, ll);
        Chi[idx] = hh;
        Clo[idx] = ll;
      }
    }
}

// ---------------------------------------------------------------------------
extern "C" void kernel_launch(void* const* d_in, const int* in_sizes, int n_in,
                              void* d_out, int out_size, void* d_ws, size_t ws_size,
                              hipStream_t stream) {
  const float* query = (const float*)d_in[0];
  const float* key   = (const float*)d_in[1];
  const float* value = (const float*)d_in[2];
  const float* Wq    = (const float*)d_in[3];
  const float* bq    = (const float*)d_in[4];
  const float* Wk    = (const float*)d_in[5];
  const float* bk    = (const float*)d_in[6];
  const float* Wv    = (const float*)d_in[7];
  const float* bv    = (const float*)d_in[8];
  const float* Wo    = (const float*)d_in[9];
  const float* bo    = (const float*)d_in[10];

  float* out  = (float*)d_out;                  // [8192][1024]
  float* attn = out + (size_t)MROWS * 1024;     // [128][1024][1024]

  short* qhi = (short*)d_ws;
  short* qlo = qhi + 8388608;
  short* khi = qlo + 8388608;
  short* klo = khi + 8388608;
  short* vt  = klo + 8388608;
  short* whi = vt  + 8388608;
  short* wlo = whi + 1048576;
  short* cxh = wlo + 1048576;   // fused path only: fresh 32MB, no alias
  short* cxl = cxh + 8388608;

  const size_t need_fused = ((size_t)7 * 8388608 + 2 * 1048576) * sizeof(short);
  const bool fuse = ws_size >= need_fused;

  const dim3 blk(256);
  const dim3 gp(512);

  convw_k<<<512, blk, 0, stream>>>(Wq, whi, wlo);
  proj_k<0, false><<<gp, blk, 0, stream>>>(query, nullptr, nullptr, whi, wlo, bq,
                                           qhi, qlo, nullptr);
  convw_k<<<512, blk, 0, stream>>>(Wk, whi, wlo);
  proj_k<0, false><<<gp, blk, 0, stream>>>(key, nullptr, nullptr, whi, wlo, bk,
                                           khi, klo, nullptr);
  convw_k<<<512, blk, 0, stream>>>(Wv, whi, wlo);
  proj_k<1, false><<<gp, blk, 0, stream>>>(value, nullptr, nullptr, whi, wlo, bv,
                                           vt, nullptr, nullptr);

  short *chFinal, *clFinal;
  if (fuse) {
    attn_k<true><<<dim3(2048), blk, 0, stream>>>(qhi, qlo, khi, klo, vt, attn,
                                                 cxh, cxl);
    chFinal = cxh; clFinal = cxl;
  } else {
    attn_k<false><<<dim3(2048), blk, 0, stream>>>(qhi, qlo, khi, klo, vt, attn,
                                                  nullptr, nullptr);
    pv2_k<<<dim3(2048), blk, 0, stream>>>(attn, vt, qhi, qlo);
    chFinal = qhi; clFinal = qlo;
  }

  convw_k<<<512, blk, 0, stream>>>(Wo, whi, wlo);
  proj_k<2, true><<<gp, blk, 0, stream>>>(nullptr, chFinal, clFinal, whi, wlo, bo,
                                          nullptr, nullptr, out);
}

// Round 6
// 464.543 us; speedup vs baseline: 3.6558x; 1.1050x over previous
//
#include <hip/hip_runtime.h>
#include <cstddef>

typedef _Float16 f16;
typedef f16 f16x8 __attribute__((ext_vector_type(8)));
typedef short s16x8 __attribute__((ext_vector_type(8)));
typedef short s16x4 __attribute__((ext_vector_type(4)));
typedef float f32x4 __attribute__((ext_vector_type(4)));

#define S_LEN 1024
#define NH 16
#define HD 64
#define MROWS 8192

__device__ __forceinline__ f32x4 mfma_f16(f16x8 a, f16x8 b, f32x4 c) {
  return __builtin_amdgcn_mfma_f32_16x16x32_f16(a, b, c, 0, 0, 0);
}
__device__ __forceinline__ short f2h(float x) {
  f16 h = (f16)x;
  return __builtin_bit_cast(short, h);
}
// x = hi + lo in fp16; residual ~2^-22|x|
__device__ __forceinline__ void splith(float x, short& h, short& l) {
  f16 hh = (f16)x;
  f16 ll = (f16)(x - (float)hh);
  h = __builtin_bit_cast(short, hh);
  l = __builtin_bit_cast(short, ll);
}

// async global->LDS DMA, 16B/lane: lane i lands at ldsbase + i*16.
typedef const __attribute__((address_space(1))) unsigned int* as1_u32p;
typedef __attribute__((address_space(3))) unsigned int* as3_u32p;
__device__ __forceinline__ void gl_lds16(const short* g, short* l) {
  __builtin_amdgcn_global_load_lds((as1_u32p)(const void*)g,
                                   (as3_u32p)(void*)l, 16, 0, 0);
}

// ---------------------------------------------------------------------------
// fp32 -> single fp16 plane in K-STEP-TILED order:
//   dst = ((nb*32 + ks)*128 + row)*32 + k
// ---------------------------------------------------------------------------
__global__ __launch_bounds__(256) void convw_k(const float* __restrict__ W,
                                               short* __restrict__ hi) {
  const int i = (blockIdx.x * 256 + threadIdx.x) * 8;
  const int n = i >> 10, kg = i & 1023;
  const int dst = (((n >> 7) * 32 + (kg >> 5)) * 128 + (n & 127)) * 32 + (kg & 31);
  float xs[8];
  *(float4*)&xs[0] = *(const float4*)&W[i];
  *(float4*)&xs[4] = *(const float4*)&W[i + 4];
  s16x8 H;
#pragma unroll
  for (int j = 0; j < 8; ++j) H[j] = f2h(xs[j]);
  *(s16x8*)&hi[dst] = H;
}

// ---------------------------------------------------------------------------
// fp16 2-term GEMM: Y = A @ W^T + bias.  acc = ah@Wh + al@Wh  (= A@Wh).
// B (single fp16 plane) via global_load_lds; APRE: A hi/lo planes DMA'd too.
// MODE 0: Q -> hi/lo fp16 planes head-major
// MODE 3: K -> single fp16 plane head-major
// MODE 1: V -> single fp16 plane per-head transposed [(bh*64+d)*1024+s]
// MODE 2: O -> fp32 [m][n]
// ---------------------------------------------------------------------------
template <int MODE, bool APRE>
__global__ __launch_bounds__(256, 2) void proj_k(
    const float* __restrict__ Af, const short* __restrict__ Ahi,
    const short* __restrict__ Alo, const short* __restrict__ Whi,
    const float* __restrict__ bias, short* __restrict__ Ohi,
    short* __restrict__ Olo, float* __restrict__ Of) {
  constexpr int AW = APRE ? 32 : 40;
  __shared__ __align__(16) short Ah[128][AW], Al[128][AW];
  __shared__ __align__(16) short Bh[128][32];
  const int t = threadIdx.x, lane = t & 63, wid = t >> 6;
  const int wr = wid >> 1, wc = wid & 1;
  const int fr = lane & 15, fg = lane >> 4;
  const int bid = blockIdx.x;                 // 512 blocks, 512%8==0
  const int wg = (bid & 7) * 64 + (bid >> 3); // XCD chunk, M-major
  const int bm = (wg >> 3) * 128, bn = (wg & 7) * 128;
  const int srow = t >> 1, sk = (t & 1) * 16;

  f32x4 acc[4][4] = {};

  for (int ks = 0; ks < 32; ++ks) {
    const int k0 = ks * 32;
    {  // B: DMA 8KB: wave w stages 1KB chunks {2w, 2w+1}
      const size_t boff = ((size_t)(bn >> 7) * 32 + ks) * 4096;
      const int c0 = wid * 2;
      gl_lds16(&Whi[boff + (size_t)c0 * 512 + lane * 8],       &Bh[0][0] + c0 * 512);
      gl_lds16(&Whi[boff + (size_t)(c0 + 1) * 512 + lane * 8], &Bh[0][0] + (c0 + 1) * 512);
    }
    if constexpr (APRE) {
      const size_t aoff = ((size_t)(bm >> 7) * 32 + ks) * 4096;
      const int c0 = wid * 2;
      gl_lds16(&Ahi[aoff + (size_t)c0 * 512 + lane * 8],       &Ah[0][0] + c0 * 512);
      gl_lds16(&Ahi[aoff + (size_t)(c0 + 1) * 512 + lane * 8], &Ah[0][0] + (c0 + 1) * 512);
      gl_lds16(&Alo[aoff + (size_t)c0 * 512 + lane * 8],       &Al[0][0] + c0 * 512);
      gl_lds16(&Alo[aoff + (size_t)(c0 + 1) * 512 + lane * 8], &Al[0][0] + (c0 + 1) * 512);
    } else {
      const float* ap = &Af[(size_t)(bm + srow) * 1024 + k0 + sk];
      float xs[16];
      *(float4*)&xs[0]  = *(const float4*)(ap);
      *(float4*)&xs[4]  = *(const float4*)(ap + 4);
      *(float4*)&xs[8]  = *(const float4*)(ap + 8);
      *(float4*)&xs[12] = *(const float4*)(ap + 12);
      s16x8 H0, L0, H1, L1;
#pragma unroll
      for (int j = 0; j < 8; ++j) { short h, l; splith(xs[j], h, l); H0[j] = h; L0[j] = l; }
#pragma unroll
      for (int j = 0; j < 8; ++j) { short h, l; splith(xs[8 + j], h, l); H1[j] = h; L1[j] = l; }
      *(s16x8*)&Ah[srow][sk] = H0; *(s16x8*)&Ah[srow][sk + 8] = H1;
      *(s16x8*)&Al[srow][sk] = L0; *(s16x8*)&Al[srow][sk + 8] = L1;
    }
    __syncthreads();
    f16x8 ah[4], al[4], bh[4];
#pragma unroll
    for (int f = 0; f < 4; ++f) {
      ah[f] = *(const f16x8*)&Ah[wr * 64 + f * 16 + fr][fg * 8];
      al[f] = *(const f16x8*)&Al[wr * 64 + f * 16 + fr][fg * 8];
      bh[f] = *(const f16x8*)&Bh[wc * 64 + f * 16 + fr][fg * 8];
    }
#pragma unroll
    for (int i = 0; i < 4; ++i)
#pragma unroll
      for (int j = 0; j < 4; ++j) {
        acc[i][j] = mfma_f16(ah[i], bh[j], acc[i][j]);
        acc[i][j] = mfma_f16(al[i], bh[j], acc[i][j]);
      }
    __syncthreads();
  }

#pragma unroll
  for (int i = 0; i < 4; ++i) {
#pragma unroll
    for (int j = 0; j < 4; ++j) {
      const int m0 = bm + wr * 64 + i * 16 + fg * 4;
      const int n  = bn + wc * 64 + j * 16 + fr;
      const float bb = bias[n];
      if constexpr (MODE == 0 || MODE == 3) {
        const int batch = m0 >> 10, s0 = m0 & 1023;
        const int h = n >> 6, d = n & 63;
        const size_t base = ((size_t)(batch * NH + h) * S_LEN + s0) * HD + d;
#pragma unroll
        for (int r = 0; r < 4; ++r) {
          const float v = acc[i][j][r] + bb;
          if constexpr (MODE == 0) {
            short hh, ll; splith(v, hh, ll);
            Ohi[base + (size_t)r * HD] = hh;
            Olo[base + (size_t)r * HD] = ll;
          } else {
            Ohi[base + (size_t)r * HD] = f2h(v);
          }
        }
      } else if constexpr (MODE == 1) {
        const int batch = m0 >> 10, s0 = m0 & 1023;
        const int h = n >> 6, d = n & 63;
        s16x4 pk;
#pragma unroll
        for (int r = 0; r < 4; ++r) pk[r] = f2h(acc[i][j][r] + bb);
        *(s16x4*)&Ohi[((size_t)(batch * NH + h) * HD + d) * S_LEN + s0] = pk;
      } else {
#pragma unroll
        for (int r = 0; r < 4; ++r)
          Of[(size_t)(m0 + r) * 1024 + n] = acc[i][j][r] + bb;
      }
    }
  }
}

// ---------------------------------------------------------------------------
// Fused attention (fp16). Transposed scores: s^T = mfma(K, Q).
// Pass 1: 1-term kh*qh -> exp -> row sums -> 1/sum.
// Pass 2: 2-term kh*qh + kh*ql -> exp*rinv -> attn (final, float4)
//         [+ PV with fp16 P,V -> ctx hi/lo tiled planes].
// ---------------------------------------------------------------------------
template <bool FUSE_PV>
__global__ __launch_bounds__(256) void attn_k(
    const short* __restrict__ Qhi, const short* __restrict__ Qlo,
    const short* __restrict__ Khi, const short* __restrict__ Vt,
    float* __restrict__ attn, short* __restrict__ Chi,
    short* __restrict__ Clo) {
  __shared__ __align__(16) short Kh[64][72];
  __shared__ __align__(16) short Vs[FUSE_PV ? 64 : 1][72];
  __shared__ __align__(16) short Pt[FUSE_PV ? 64 : 1][72];
  __shared__ float sums[2][64];
  __shared__ float sinv[64];

  const int wg = blockIdx.x;                    // 2048 blocks
  const int w  = (wg & 7) * 256 + (wg >> 3);    // bijective XCD chunking
  const int bh = w >> 4;
  const int qb = (w & 15) * 64;
  const int batch = bh >> 4, h = bh & 15;

  const int t = threadIdx.x, lane = t & 63, wid = t >> 6;
  const int wq = wid >> 1, wk = wid & 1;
  const int fr = lane & 15, fg = lane >> 4;
  const int srow = t >> 2, sc = (t & 3) * 16;

  f16x8 qh[2][2], ql[2][2];
#pragma unroll
  for (int fm = 0; fm < 2; ++fm)
#pragma unroll
    for (int kc = 0; kc < 2; ++kc) {
      const size_t qa =
          ((size_t)bh * S_LEN + qb + wq * 32 + fm * 16 + fr) * HD + kc * 32 + fg * 8;
      qh[fm][kc] = *(const f16x8*)&Qhi[qa];
      ql[fm][kc] = *(const f16x8*)&Qlo[qa];
    }

  // ---------------- pass 1: cheap row sums ----------------
  float rs[2] = {};
  for (int kt = 0; kt < 16; ++kt) {
    const size_t kb = ((size_t)bh * S_LEN + kt * 64 + srow) * HD + sc;
    const s16x8 h0 = *(const s16x8*)&Khi[kb];
    const s16x8 h1 = *(const s16x8*)&Khi[kb + 8];
    *(s16x8*)&Kh[srow][sc] = h0; *(s16x8*)&Kh[srow][sc + 8] = h1;
    __syncthreads();
    f16x8 kh[2][2];
#pragma unroll
    for (int fn = 0; fn < 2; ++fn)
#pragma unroll
      for (int kc = 0; kc < 2; ++kc)
        kh[fn][kc] = *(const f16x8*)&Kh[wk * 32 + fn * 16 + fr][kc * 32 + fg * 8];
    f32x4 s4[2][2] = {};  // [fn][fm]
#pragma unroll
    for (int fn = 0; fn < 2; ++fn)
#pragma unroll
      for (int fm = 0; fm < 2; ++fm)
#pragma unroll
        for (int kc = 0; kc < 2; ++kc)
          s4[fn][fm] = mfma_f16(kh[fn][kc], qh[fm][kc], s4[fn][fm]);
#pragma unroll
    for (int fn = 0; fn < 2; ++fn)
#pragma unroll
      for (int fm = 0; fm < 2; ++fm)
#pragma unroll
        for (int r = 0; r < 4; ++r)
          rs[fm] += __expf(s4[fn][fm][r] * 0.125f);
    __syncthreads();
  }
#pragma unroll
  for (int fm = 0; fm < 2; ++fm) {
    float v = rs[fm];
    v += __shfl_xor(v, 16); v += __shfl_xor(v, 32);
    if (fg == 0) sums[wk][wq * 32 + fm * 16 + fr] = v;
  }
  __syncthreads();
  if (t < 64) sinv[t] = 1.0f / (sums[0][t] + sums[1][t]);
  __syncthreads();

  float pinv[2];
#pragma unroll
  for (int fm = 0; fm < 2; ++fm) pinv[fm] = sinv[wq * 32 + fm * 16 + fr];

  // ---------------- pass 2: exact scores + attn write (+ PV) ----------------
  f32x4 apv[2][2] = {};
  for (int kt = 0; kt < 16; ++kt) {
    {
      const size_t kb = ((size_t)bh * S_LEN + kt * 64 + srow) * HD + sc;
      const s16x8 h0 = *(const s16x8*)&Khi[kb];
      const s16x8 h1 = *(const s16x8*)&Khi[kb + 8];
      *(s16x8*)&Kh[srow][sc] = h0; *(s16x8*)&Kh[srow][sc + 8] = h1;
      if constexpr (FUSE_PV) {
        const short* vrow = Vt + ((size_t)bh * HD + srow) * S_LEN + kt * 64 + sc;
        const s16x8 v0 = *(const s16x8*)(vrow);
        const s16x8 v1 = *(const s16x8*)(vrow + 8);
        *(s16x8*)&Vs[srow][sc] = v0; *(s16x8*)&Vs[srow][sc + 8] = v1;
      }
    }
    __syncthreads();
    f16x8 kh[2][2];
#pragma unroll
    for (int fn = 0; fn < 2; ++fn)
#pragma unroll
      for (int kc = 0; kc < 2; ++kc)
        kh[fn][kc] = *(const f16x8*)&Kh[wk * 32 + fn * 16 + fr][kc * 32 + fg * 8];
    f32x4 s4[2][2] = {};  // [fn][fm]
#pragma unroll
    for (int fn = 0; fn < 2; ++fn)
#pragma unroll
      for (int fm = 0; fm < 2; ++fm)
#pragma unroll
        for (int kc = 0; kc < 2; ++kc) {
          s4[fn][fm] = mfma_f16(kh[fn][kc], qh[fm][kc], s4[fn][fm]);
          s4[fn][fm] = mfma_f16(kh[fn][kc], ql[fm][kc], s4[fn][fm]);
        }
#pragma unroll
    for (int fm = 0; fm < 2; ++fm) {
      const int q = qb + wq * 32 + fm * 16 + fr;
#pragma unroll
      for (int fn = 0; fn < 2; ++fn) {
        const int kbase = wk * 32 + fn * 16 + fg * 4;
        float4 e4;
        e4.x = __expf(s4[fn][fm][0] * 0.125f) * pinv[fm];
        e4.y = __expf(s4[fn][fm][1] * 0.125f) * pinv[fm];
        e4.z = __expf(s4[fn][fm][2] * 0.125f) * pinv[fm];
        e4.w = __expf(s4[fn][fm][3] * 0.125f) * pinv[fm];
        *(float4*)&attn[((size_t)bh * S_LEN + q) * S_LEN + kt * 64 + kbase] = e4;
        if constexpr (FUSE_PV) {
          s16x4 pk;
          pk[0] = f2h(e4.x); pk[1] = f2h(e4.y);
          pk[2] = f2h(e4.z); pk[3] = f2h(e4.w);
          *(s16x4*)&Pt[wq * 32 + fm * 16 + fr][kbase] = pk;
        }
      }
    }
    __syncthreads();
    if constexpr (FUSE_PV) {
      f16x8 af[2][2], bv[2][2];
#pragma unroll
      for (int f = 0; f < 2; ++f)
#pragma unroll
        for (int kc = 0; kc < 2; ++kc) {
          af[f][kc] = *(const f16x8*)&Pt[wq * 32 + f * 16 + fr][kc * 32 + fg * 8];
          bv[f][kc] = *(const f16x8*)&Vs[wk * 32 + f * 16 + fr][kc * 32 + fg * 8];
        }
#pragma unroll
      for (int i = 0; i < 2; ++i)
#pragma unroll
        for (int j = 0; j < 2; ++j)
#pragma unroll
          for (int kc = 0; kc < 2; ++kc)
            apv[i][j] = mfma_f16(af[i][kc], bv[j][kc], apv[i][j]);
      __syncthreads();
    }
  }

  if constexpr (FUSE_PV) {
#pragma unroll
    for (int i = 0; i < 2; ++i)
#pragma unroll
      for (int j = 0; j < 2; ++j) {
        const int s0 = qb + wq * 32 + i * 16 + fg * 4;
        const int d = h * HD + wk * 32 + j * 16 + fr;
#pragma unroll
        for (int r = 0; r < 4; ++r) {
          const int m = batch * S_LEN + s0 + r;
          const size_t idx =
              (((size_t)(m >> 7) * 32 + (d >> 5)) * 128 + (m & 127)) * 32 + (d & 31);
          short hh, ll; splith(apv[i][j][r], hh, ll);
          Chi[idx] = hh;
          Clo[idx] = ll;
        }
      }
  }
}

// ---------------------------------------------------------------------------
// Fallback PV (split path, fp16): attn fp32 -> f2h, MFMA with V -> ctx planes.
// ---------------------------------------------------------------------------
__global__ __launch_bounds__(256) void pv2_k(
    const float* __restrict__ attn, const short* __restrict__ Vt,
    short* __restrict__ Chi, short* __restrict__ Clo) {
  __shared__ __align__(16) short At[64][72], Vs[64][72];
  const int wg = blockIdx.x;
  const int w  = (wg & 7) * 256 + (wg >> 3);
  const int bh = w >> 4;
  const int qb = (w & 15) * 64;
  const int batch = bh >> 4, h = bh & 15;
  const int t = threadIdx.x, lane = t & 63, wid = t >> 6;
  const int wq = wid >> 1, wd = wid & 1;
  const int fr = lane & 15, fg = lane >> 4;
  const int srow = t >> 2, sc = (t & 3) * 16;
  const float* arow = attn + ((size_t)bh * S_LEN + qb + srow) * S_LEN + sc;
  const short* vrow = Vt + ((size_t)bh * HD + srow) * S_LEN + sc;

  f32x4 acc[2][2] = {};
  for (int kt = 0; kt < 16; ++kt) {
    float xs[16];
    *(float4*)&xs[0]  = *(const float4*)(arow + kt * 64);
    *(float4*)&xs[4]  = *(const float4*)(arow + kt * 64 + 4);
    *(float4*)&xs[8]  = *(const float4*)(arow + kt * 64 + 8);
    *(float4*)&xs[12] = *(const float4*)(arow + kt * 64 + 12);
    s16x8 c0, c1;
#pragma unroll
    for (int j = 0; j < 8; ++j) { c0[j] = f2h(xs[j]); c1[j] = f2h(xs[8 + j]); }
    const s16x8 v0 = *(const s16x8*)(vrow + kt * 64);
    const s16x8 v1 = *(const s16x8*)(vrow + kt * 64 + 8);
    *(s16x8*)&At[srow][sc] = c0; *(s16x8*)&At[srow][sc + 8] = c1;
    *(s16x8*)&Vs[srow][sc] = v0; *(s16x8*)&Vs[srow][sc + 8] = v1;
    __syncthreads();
    f16x8 af[2][2], bv[2][2];
#pragma unroll
    for (int f = 0; f < 2; ++f)
#pragma unroll
      for (int kc = 0; kc < 2; ++kc) {
        af[f][kc] = *(const f16x8*)&At[wq * 32 + f * 16 + fr][kc * 32 + fg * 8];
        bv[f][kc] = *(const f16x8*)&Vs[wd * 32 + f * 16 + fr][kc * 32 + fg * 8];
      }
#pragma unroll
    for (int i = 0; i < 2; ++i)
#pragma unroll
      for (int j = 0; j < 2; ++j)
#pragma unroll
        for (int kc = 0; kc < 2; ++kc)
          acc[i][j] = mfma_f16(af[i][kc], bv[j][kc], acc[i][j]);
    __syncthreads();
  }

#pragma unroll
  for (int i = 0; i < 2; ++i)
#pragma unroll
    for (int j = 0; j < 2; ++j) {
      const int s0 = qb + wq * 32 + i * 16 + fg * 4;
      const int d = h * HD + wd * 32 + j * 16 + fr;
#pragma unroll
      for (int r = 0; r < 4; ++r) {
        const int m = batch * S_LEN + s0 + r;
        const size_t idx =
            (((size_t)(m >> 7) * 32 + (d >> 5)) * 128 + (m & 127)) * 32 + (d & 31);
        short hh, ll; splith(acc[i][j][r], hh, ll);
        Chi[idx] = hh;
        Clo[idx] = ll;
      }
    }
}

// ---------------------------------------------------------------------------
extern "C" void kernel_launch(void* const* d_in, const int* in_sizes, int n_in,
                              void* d_out, int out_size, void* d_ws, size_t ws_size,
                              hipStream_t stream) {
  const float* query = (const float*)d_in[0];
  const float* key   = (const float*)d_in[1];
  const float* value = (const float*)d_in[2];
  const float* Wq    = (const float*)d_in[3];
  const float* bq    = (const float*)d_in[4];
  const float* Wk    = (const float*)d_in[5];
  const float* bk    = (const float*)d_in[6];
  const float* Wv    = (const float*)d_in[7];
  const float* bv    = (const float*)d_in[8];
  const float* Wo    = (const float*)d_in[9];
  const float* bo    = (const float*)d_in[10];

  float* out  = (float*)d_out;                  // [8192][1024]
  float* attn = out + (size_t)MROWS * 1024;     // [128][1024][1024]

  short* qhi = (short*)d_ws;                    // fp16 planes (bit-stored)
  short* qlo = qhi + 8388608;
  short* khi = qlo + 8388608;
  short* vt  = khi + 8388608;
  short* whi = vt  + 8388608;
  short* cxh = whi + 1048576;   // fused path: fresh slabs, no alias
  short* cxl = cxh + 8388608;

  const size_t need_fused = ((size_t)6 * 8388608 + 1048576) * sizeof(short);
  const bool fuse = ws_size >= need_fused;

  const dim3 blk(256);
  const dim3 gp(512);

  convw_k<<<512, blk, 0, stream>>>(Wq, whi);
  proj_k<0, false><<<gp, blk, 0, stream>>>(query, nullptr, nullptr, whi, bq,
                                           qhi, qlo, nullptr);
  convw_k<<<512, blk, 0, stream>>>(Wk, whi);
  proj_k<3, false><<<gp, blk, 0, stream>>>(key, nullptr, nullptr, whi, bk,
                                           khi, nullptr, nullptr);
  convw_k<<<512, blk, 0, stream>>>(Wv, whi);
  proj_k<1, false><<<gp, blk, 0, stream>>>(value, nullptr, nullptr, whi, bv,
                                           vt, nullptr, nullptr);

  short *chFinal, *clFinal;
  if (fuse) {
    attn_k<true><<<dim3(2048), blk, 0, stream>>>(qhi, qlo, khi, vt, attn,
                                                 cxh, cxl);
    chFinal = cxh; clFinal = cxl;
  } else {
    attn_k<false><<<dim3(2048), blk, 0, stream>>>(qhi, qlo, khi, vt, attn,
                                                  nullptr, nullptr);
    // ctx aliases Q planes — safe across kernel boundary (Q dead now)
    pv2_k<<<dim3(2048), blk, 0, stream>>>(attn, vt, qhi, qlo);
    chFinal = qhi; clFinal = qlo;
  }

  convw_k<<<512, blk, 0, stream>>>(Wo, whi);
  proj_k<2, true><<<gp, blk, 0, stream>>>(nullptr, chFinal, clFinal, whi, bo,
                                          nullptr, nullptr, out);
}

// Round 7
// 385.594 us; speedup vs baseline: 4.4043x; 1.2047x over previous
//
#include <hip/hip_runtime.h>
#include <cstddef>

typedef _Float16 f16;
typedef f16 f16x8 __attribute__((ext_vector_type(8)));
typedef short s16x8 __attribute__((ext_vector_type(8)));
typedef short s16x4 __attribute__((ext_vector_type(4)));
typedef float f32x4 __attribute__((ext_vector_type(4)));

#define S_LEN 1024
#define NH 16
#define HD 64
#define MROWS 8192
#define WPLANE 1048576

__device__ __forceinline__ f32x4 mfma_f16(f16x8 a, f16x8 b, f32x4 c) {
  return __builtin_amdgcn_mfma_f32_16x16x32_f16(a, b, c, 0, 0, 0);
}
__device__ __forceinline__ short f2h(float x) {
  f16 h = (f16)x;
  return __builtin_bit_cast(short, h);
}

// async global->LDS DMA, 16B/lane: lane i lands at ldsbase + i*16.
typedef const __attribute__((address_space(1))) unsigned int* as1_u32p;
typedef __attribute__((address_space(3))) unsigned int* as3_u32p;
__device__ __forceinline__ void gl_lds16(const short* g, short* l) {
  __builtin_amdgcn_global_load_lds((as1_u32p)(const void*)g,
                                   (as3_u32p)(void*)l, 16, 0, 0);
}

// ---------------------------------------------------------------------------
// All 4 weights fp32 -> packed fp16 planes in K-STEP-TILED order:
//   dst = wsel*WPLANE + ((nb*32 + ks)*128 + row)*32 + k
// grid (512, 4).
// ---------------------------------------------------------------------------
__global__ __launch_bounds__(256) void convw4_k(
    const float* __restrict__ W0, const float* __restrict__ W1,
    const float* __restrict__ W2, const float* __restrict__ W3,
    short* __restrict__ out) {
  const int wsel = blockIdx.y;
  const float* W = wsel == 0 ? W0 : (wsel == 1 ? W1 : (wsel == 2 ? W2 : W3));
  const int i = (blockIdx.x * 256 + threadIdx.x) * 8;
  const int n = i >> 10, kg = i & 1023;
  const int dst = (((n >> 7) * 32 + (kg >> 5)) * 128 + (n & 127)) * 32 + (kg & 31);
  float xs[8];
  *(float4*)&xs[0] = *(const float4*)&W[i];
  *(float4*)&xs[4] = *(const float4*)&W[i + 4];
  s16x8 H;
#pragma unroll
  for (int j = 0; j < 8; ++j) H[j] = f2h(xs[j]);
  *(s16x8*)&out[(size_t)wsel * WPLANE + dst] = H;
}

// ---------------------------------------------------------------------------
// Merged Q/K/V projection, pure fp16 1-term: Y = f16(A) @ f16(W)^T + bias.
// grid (512, 3): y = pid selects {query,key,value}. A fp32 reg-staged -> fp16
// LDS; B via global_load_lds from packed tiled planes.
// pid 0/1 -> head-major plane [(b*16+h)*1024+s]*64+d ; pid 2 -> V^T plane.
// ---------------------------------------------------------------------------
__global__ __launch_bounds__(256, 2) void qkvproj_k(
    const float* __restrict__ Aq, const float* __restrict__ Ak,
    const float* __restrict__ Av, const short* __restrict__ Wpl,
    const float* __restrict__ bq, const float* __restrict__ bk,
    const float* __restrict__ bv, short* __restrict__ Oq,
    short* __restrict__ Ok, short* __restrict__ Ovt) {
  __shared__ __align__(16) short Ah[128][40];
  __shared__ __align__(16) short Bh[128][32];
  const int pid = blockIdx.y;
  const float* Af = pid == 0 ? Aq : (pid == 1 ? Ak : Av);
  const float* bias = pid == 0 ? bq : (pid == 1 ? bk : bv);
  const short* Whi = Wpl + (size_t)pid * WPLANE;

  const int t = threadIdx.x, lane = t & 63, wid = t >> 6;
  const int wr = wid >> 1, wc = wid & 1;
  const int fr = lane & 15, fg = lane >> 4;
  const int bid = blockIdx.x;                 // 512 blocks, 512%8==0
  const int wg = (bid & 7) * 64 + (bid >> 3); // XCD chunk, M-major
  const int bm = (wg >> 3) * 128, bn = (wg & 7) * 128;
  const int srow = t >> 1, sk = (t & 1) * 16;

  f32x4 acc[4][4] = {};

  for (int ks = 0; ks < 32; ++ks) {
    const int k0 = ks * 32;
    {  // B: DMA 8KB: wave w stages 1KB chunks {2w, 2w+1}
      const size_t boff = ((size_t)(bn >> 7) * 32 + ks) * 4096;
      const int c0 = wid * 2;
      gl_lds16(&Whi[boff + (size_t)c0 * 512 + lane * 8],       &Bh[0][0] + c0 * 512);
      gl_lds16(&Whi[boff + (size_t)(c0 + 1) * 512 + lane * 8], &Bh[0][0] + (c0 + 1) * 512);
    }
    {
      const float* ap = &Af[(size_t)(bm + srow) * 1024 + k0 + sk];
      float xs[16];
      *(float4*)&xs[0]  = *(const float4*)(ap);
      *(float4*)&xs[4]  = *(const float4*)(ap + 4);
      *(float4*)&xs[8]  = *(const float4*)(ap + 8);
      *(float4*)&xs[12] = *(const float4*)(ap + 12);
      s16x8 H0, H1;
#pragma unroll
      for (int j = 0; j < 8; ++j) { H0[j] = f2h(xs[j]); H1[j] = f2h(xs[8 + j]); }
      *(s16x8*)&Ah[srow][sk] = H0; *(s16x8*)&Ah[srow][sk + 8] = H1;
    }
    __syncthreads();
    f16x8 ah[4], bh[4];
#pragma unroll
    for (int f = 0; f < 4; ++f) {
      ah[f] = *(const f16x8*)&Ah[wr * 64 + f * 16 + fr][fg * 8];
      bh[f] = *(const f16x8*)&Bh[wc * 64 + f * 16 + fr][fg * 8];
    }
#pragma unroll
    for (int i = 0; i < 4; ++i)
#pragma unroll
      for (int j = 0; j < 4; ++j)
        acc[i][j] = mfma_f16(ah[i], bh[j], acc[i][j]);
    __syncthreads();
  }

#pragma unroll
  for (int i = 0; i < 4; ++i) {
#pragma unroll
    for (int j = 0; j < 4; ++j) {
      const int m0 = bm + wr * 64 + i * 16 + fg * 4;
      const int n  = bn + wc * 64 + j * 16 + fr;
      const float bb = bias[n];
      const int batch = m0 >> 10, s0 = m0 & 1023;
      const int h = n >> 6, d = n & 63;
      if (pid < 2) {
        short* O = pid == 0 ? Oq : Ok;
        const size_t base = ((size_t)(batch * NH + h) * S_LEN + s0) * HD + d;
#pragma unroll
        for (int r = 0; r < 4; ++r)
          O[base + (size_t)r * HD] = f2h(acc[i][j][r] + bb);
      } else {
        s16x4 pk;
#pragma unroll
        for (int r = 0; r < 4; ++r) pk[r] = f2h(acc[i][j][r] + bb);
        *(s16x4*)&Ovt[((size_t)(batch * NH + h) * HD + d) * S_LEN + s0] = pk;
      }
    }
  }
}

// ---------------------------------------------------------------------------
// O projection, pure fp16 1-term: out = f16(ctx) @ f16(Wo)^T + bo (fp32 out).
// Both operands DMA'd from tiled planes.
// ---------------------------------------------------------------------------
__global__ __launch_bounds__(256, 2) void oproj_k(
    const short* __restrict__ Ahi, const short* __restrict__ Whi,
    const float* __restrict__ bias, float* __restrict__ Of) {
  __shared__ __align__(16) short Ah[128][32];
  __shared__ __align__(16) short Bh[128][32];
  const int t = threadIdx.x, lane = t & 63, wid = t >> 6;
  const int wr = wid >> 1, wc = wid & 1;
  const int fr = lane & 15, fg = lane >> 4;
  const int bid = blockIdx.x;
  const int wg = (bid & 7) * 64 + (bid >> 3);
  const int bm = (wg >> 3) * 128, bn = (wg & 7) * 128;

  f32x4 acc[4][4] = {};

  for (int ks = 0; ks < 32; ++ks) {
    {
      const size_t boff = ((size_t)(bn >> 7) * 32 + ks) * 4096;
      const size_t aoff = ((size_t)(bm >> 7) * 32 + ks) * 4096;
      const int c0 = wid * 2;
      gl_lds16(&Whi[boff + (size_t)c0 * 512 + lane * 8],       &Bh[0][0] + c0 * 512);
      gl_lds16(&Whi[boff + (size_t)(c0 + 1) * 512 + lane * 8], &Bh[0][0] + (c0 + 1) * 512);
      gl_lds16(&Ahi[aoff + (size_t)c0 * 512 + lane * 8],       &Ah[0][0] + c0 * 512);
      gl_lds16(&Ahi[aoff + (size_t)(c0 + 1) * 512 + lane * 8], &Ah[0][0] + (c0 + 1) * 512);
    }
    __syncthreads();
    f16x8 ah[4], bh[4];
#pragma unroll
    for (int f = 0; f < 4; ++f) {
      ah[f] = *(const f16x8*)&Ah[wr * 64 + f * 16 + fr][fg * 8];
      bh[f] = *(const f16x8*)&Bh[wc * 64 + f * 16 + fr][fg * 8];
    }
#pragma unroll
    for (int i = 0; i < 4; ++i)
#pragma unroll
      for (int j = 0; j < 4; ++j)
        acc[i][j] = mfma_f16(ah[i], bh[j], acc[i][j]);
    __syncthreads();
  }

#pragma unroll
  for (int i = 0; i < 4; ++i) {
#pragma unroll
    for (int j = 0; j < 4; ++j) {
      const int m0 = bm + wr * 64 + i * 16 + fg * 4;
      const int n  = bn + wc * 64 + j * 16 + fr;
      const float bb = bias[n];
#pragma unroll
      for (int r = 0; r < 4; ++r)
        Of[(size_t)(m0 + r) * 1024 + n] = acc[i][j][r] + bb;
    }
  }
}

// ---------------------------------------------------------------------------
// Fused attention, pure fp16. Transposed scores: s^T = mfma(K, Q).
// Pass 1: scores -> exp -> row sums -> 1/sum.   (same MFMA as pass 2 ->
// denominators exactly consistent with stored numerators)
// Pass 2: scores -> exp*rinv -> attn (final, float4) [+ PV -> ctx plane].
// ---------------------------------------------------------------------------
template <bool FUSE_PV>
__global__ __launch_bounds__(256) void attn_k(
    const short* __restrict__ Qp, const short* __restrict__ Kp,
    const short* __restrict__ Vt, float* __restrict__ attn,
    short* __restrict__ Cp) {
  __shared__ __align__(16) short Kh[64][72];
  __shared__ __align__(16) short Vs[FUSE_PV ? 64 : 1][72];
  __shared__ __align__(16) short Pt[FUSE_PV ? 64 : 1][72];
  __shared__ float sums[2][64];
  __shared__ float sinv[64];

  const int wg = blockIdx.x;                    // 2048 blocks
  const int w  = (wg & 7) * 256 + (wg >> 3);    // bijective XCD chunking
  const int bh = w >> 4;
  const int qb = (w & 15) * 64;
  const int batch = bh >> 4, h = bh & 15;

  const int t = threadIdx.x, lane = t & 63, wid = t >> 6;
  const int wq = wid >> 1, wk = wid & 1;
  const int fr = lane & 15, fg = lane >> 4;
  const int srow = t >> 2, sc = (t & 3) * 16;

  f16x8 qh[2][2];
#pragma unroll
  for (int fm = 0; fm < 2; ++fm)
#pragma unroll
    for (int kc = 0; kc < 2; ++kc) {
      const size_t qa =
          ((size_t)bh * S_LEN + qb + wq * 32 + fm * 16 + fr) * HD + kc * 32 + fg * 8;
      qh[fm][kc] = *(const f16x8*)&Qp[qa];
    }

  // ---------------- pass 1: row sums ----------------
  float rs[2] = {};
  for (int kt = 0; kt < 16; ++kt) {
    const size_t kb = ((size_t)bh * S_LEN + kt * 64 + srow) * HD + sc;
    const s16x8 h0 = *(const s16x8*)&Kp[kb];
    const s16x8 h1 = *(const s16x8*)&Kp[kb + 8];
    *(s16x8*)&Kh[srow][sc] = h0; *(s16x8*)&Kh[srow][sc + 8] = h1;
    __syncthreads();
    f16x8 kh[2][2];
#pragma unroll
    for (int fn = 0; fn < 2; ++fn)
#pragma unroll
      for (int kc = 0; kc < 2; ++kc)
        kh[fn][kc] = *(const f16x8*)&Kh[wk * 32 + fn * 16 + fr][kc * 32 + fg * 8];
    f32x4 s4[2][2] = {};  // [fn][fm]
#pragma unroll
    for (int fn = 0; fn < 2; ++fn)
#pragma unroll
      for (int fm = 0; fm < 2; ++fm)
#pragma unroll
        for (int kc = 0; kc < 2; ++kc)
          s4[fn][fm] = mfma_f16(kh[fn][kc], qh[fm][kc], s4[fn][fm]);
#pragma unroll
    for (int fn = 0; fn < 2; ++fn)
#pragma unroll
      for (int fm = 0; fm < 2; ++fm)
#pragma unroll
        for (int r = 0; r < 4; ++r)
          rs[fm] += __expf(s4[fn][fm][r] * 0.125f);
    __syncthreads();
  }
#pragma unroll
  for (int fm = 0; fm < 2; ++fm) {
    float v = rs[fm];
    v += __shfl_xor(v, 16); v += __shfl_xor(v, 32);
    if (fg == 0) sums[wk][wq * 32 + fm * 16 + fr] = v;
  }
  __syncthreads();
  if (t < 64) sinv[t] = 1.0f / (sums[0][t] + sums[1][t]);
  __syncthreads();

  float pinv[2];
#pragma unroll
  for (int fm = 0; fm < 2; ++fm) pinv[fm] = sinv[wq * 32 + fm * 16 + fr];

  // ---------------- pass 2: scores + attn write (+ PV) ----------------
  f32x4 apv[2][2] = {};
  for (int kt = 0; kt < 16; ++kt) {
    {
      const size_t kb = ((size_t)bh * S_LEN + kt * 64 + srow) * HD + sc;
      const s16x8 h0 = *(const s16x8*)&Kp[kb];
      const s16x8 h1 = *(const s16x8*)&Kp[kb + 8];
      *(s16x8*)&Kh[srow][sc] = h0; *(s16x8*)&Kh[srow][sc + 8] = h1;
      if constexpr (FUSE_PV) {
        const short* vrow = Vt + ((size_t)bh * HD + srow) * S_LEN + kt * 64 + sc;
        const s16x8 v0 = *(const s16x8*)(vrow);
        const s16x8 v1 = *(const s16x8*)(vrow + 8);
        *(s16x8*)&Vs[srow][sc] = v0; *(s16x8*)&Vs[srow][sc + 8] = v1;
      }
    }
    __syncthreads();
    f16x8 kh[2][2];
#pragma unroll
    for (int fn = 0; fn < 2; ++fn)
#pragma unroll
      for (int kc = 0; kc < 2; ++kc)
        kh[fn][kc] = *(const f16x8*)&Kh[wk * 32 + fn * 16 + fr][kc * 32 + fg * 8];
    f32x4 s4[2][2] = {};  // [fn][fm]
#pragma unroll
    for (int fn = 0; fn < 2; ++fn)
#pragma unroll
      for (int fm = 0; fm < 2; ++fm)
#pragma unroll
        for (int kc = 0; kc < 2; ++kc)
          s4[fn][fm] = mfma_f16(kh[fn][kc], qh[fm][kc], s4[fn][fm]);
#pragma unroll
    for (int fm = 0; fm < 2; ++fm) {
      const int q = qb + wq * 32 + fm * 16 + fr;
#pragma unroll
      for (int fn = 0; fn < 2; ++fn) {
        const int kbase = wk * 32 + fn * 16 + fg * 4;
        float4 e4;
        e4.x = __expf(s4[fn][fm][0] * 0.125f) * pinv[fm];
        e4.y = __expf(s4[fn][fm][1] * 0.125f) * pinv[fm];
        e4.z = __expf(s4[fn][fm][2] * 0.125f) * pinv[fm];
        e4.w = __expf(s4[fn][fm][3] * 0.125f) * pinv[fm];
        *(float4*)&attn[((size_t)bh * S_LEN + q) * S_LEN + kt * 64 + kbase] = e4;
        if constexpr (FUSE_PV) {
          s16x4 pk;
          pk[0] = f2h(e4.x); pk[1] = f2h(e4.y);
          pk[2] = f2h(e4.z); pk[3] = f2h(e4.w);
          *(s16x4*)&Pt[wq * 32 + fm * 16 + fr][kbase] = pk;
        }
      }
    }
    __syncthreads();
    if constexpr (FUSE_PV) {
      f16x8 af[2][2], bv[2][2];
#pragma unroll
      for (int f = 0; f < 2; ++f)
#pragma unroll
        for (int kc = 0; kc < 2; ++kc) {
          af[f][kc] = *(const f16x8*)&Pt[wq * 32 + f * 16 + fr][kc * 32 + fg * 8];
          bv[f][kc] = *(const f16x8*)&Vs[wk * 32 + f * 16 + fr][kc * 32 + fg * 8];
        }
#pragma unroll
      for (int i = 0; i < 2; ++i)
#pragma unroll
        for (int j = 0; j < 2; ++j)
#pragma unroll
          for (int kc = 0; kc < 2; ++kc)
            apv[i][j] = mfma_f16(af[i][kc], bv[j][kc], apv[i][j]);
      __syncthreads();
    }
  }

  if constexpr (FUSE_PV) {
    // ctx -> single fp16 plane in K-STEP-TILED order for the O-proj DMA
#pragma unroll
    for (int i = 0; i < 2; ++i)
#pragma unroll
      for (int j = 0; j < 2; ++j) {
        const int s0 = qb + wq * 32 + i * 16 + fg * 4;
        const int d = h * HD + wk * 32 + j * 16 + fr;
#pragma unroll
        for (int r = 0; r < 4; ++r) {
          const int m = batch * S_LEN + s0 + r;
          const size_t idx =
              (((size_t)(m >> 7) * 32 + (d >> 5)) * 128 + (m & 127)) * 32 + (d & 31);
          Cp[idx] = f2h(apv[i][j][r]);
        }
      }
  }
}

// ---------------------------------------------------------------------------
// Fallback PV (split path): attn fp32 -> f16, MFMA with V -> ctx plane.
// ---------------------------------------------------------------------------
__global__ __launch_bounds__(256) void pv2_k(
    const float* __restrict__ attn, const short* __restrict__ Vt,
    short* __restrict__ Cp) {
  __shared__ __align__(16) short At[64][72], Vs[64][72];
  const int wg = blockIdx.x;
  const int w  = (wg & 7) * 256 + (wg >> 3);
  const int bh = w >> 4;
  const int qb = (w & 15) * 64;
  const int batch = bh >> 4, h = bh & 15;
  const int t = threadIdx.x, lane = t & 63, wid = t >> 6;
  const int wq = wid >> 1, wd = wid & 1;
  const int fr = lane & 15, fg = lane >> 4;
  const int srow = t >> 2, sc = (t & 3) * 16;
  const float* arow = attn + ((size_t)bh * S_LEN + qb + srow) * S_LEN + sc;
  const short* vrow = Vt + ((size_t)bh * HD + srow) * S_LEN + sc;

  f32x4 acc[2][2] = {};
  for (int kt = 0; kt < 16; ++kt) {
    float xs[16];
    *(float4*)&xs[0]  = *(const float4*)(arow + kt * 64);
    *(float4*)&xs[4]  = *(const float4*)(arow + kt * 64 + 4);
    *(float4*)&xs[8]  = *(const float4*)(arow + kt * 64 + 8);
    *(float4*)&xs[12] = *(const float4*)(arow + kt * 64 + 12);
    s16x8 c0, c1;
#pragma unroll
    for (int j = 0; j < 8; ++j) { c0[j] = f2h(xs[j]); c1[j] = f2h(xs[8 + j]); }
    const s16x8 v0 = *(const s16x8*)(vrow + kt * 64);
    const s16x8 v1 = *(const s16x8*)(vrow + kt * 64 + 8);
    *(s16x8*)&At[srow][sc] = c0; *(s16x8*)&At[srow][sc + 8] = c1;
    *(s16x8*)&Vs[srow][sc] = v0; *(s16x8*)&Vs[srow][sc + 8] = v1;
    __syncthreads();
    f16x8 af[2][2], bv[2][2];
#pragma unroll
    for (int f = 0; f < 2; ++f)
#pragma unroll
      for (int kc = 0; kc < 2; ++kc) {
        af[f][kc] = *(const f16x8*)&At[wq * 32 + f * 16 + fr][kc * 32 + fg * 8];
        bv[f][kc] = *(const f16x8*)&Vs[wd * 32 + f * 16 + fr][kc * 32 + fg * 8];
      }
#pragma unroll
    for (int i = 0; i < 2; ++i)
#pragma unroll
      for (int j = 0; j < 2; ++j)
#pragma unroll
        for (int kc = 0; kc < 2; ++kc)
          acc[i][j] = mfma_f16(af[i][kc], bv[j][kc], acc[i][j]);
    __syncthreads();
  }

#pragma unroll
  for (int i = 0; i < 2; ++i)
#pragma unroll
    for (int j = 0; j < 2; ++j) {
      const int s0 = qb + wq * 32 + i * 16 + fg * 4;
      const int d = h * HD + wd * 32 + j * 16 + fr;
#pragma unroll
      for (int r = 0; r < 4; ++r) {
        const int m = batch * S_LEN + s0 + r;
        const size_t idx =
            (((size_t)(m >> 7) * 32 + (d >> 5)) * 128 + (m & 127)) * 32 + (d & 31);
        Cp[idx] = f2h(acc[i][j][r]);
      }
    }
}

// ---------------------------------------------------------------------------
extern "C" void kernel_launch(void* const* d_in, const int* in_sizes, int n_in,
                              void* d_out, int out_size, void* d_ws, size_t ws_size,
                              hipStream_t stream) {
  const float* query = (const float*)d_in[0];
  const float* key   = (const float*)d_in[1];
  const float* value = (const float*)d_in[2];
  const float* Wq    = (const float*)d_in[3];
  const float* bq    = (const float*)d_in[4];
  const float* Wk    = (const float*)d_in[5];
  const float* bk    = (const float*)d_in[6];
  const float* Wv    = (const float*)d_in[7];
  const float* bv    = (const float*)d_in[8];
  const float* Wo    = (const float*)d_in[9];
  const float* bo    = (const float*)d_in[10];

  float* out  = (float*)d_out;                  // [8192][1024]
  float* attn = out + (size_t)MROWS * 1024;     // [128][1024][1024]

  short* qp = (short*)d_ws;                     // fp16 planes (bit-stored)
  short* kp = qp + 8388608;
  short* vt = kp + 8388608;
  short* w4 = vt + 8388608;                     // 4 packed weight planes
  short* cx = w4 + 4 * WPLANE;                  // ctx plane (fused: no alias)

  const size_t need_fused = ((size_t)4 * 8388608 + 4 * WPLANE) * sizeof(short);
  const bool fuse = ws_size >= need_fused;

  const dim3 blk(256);

  convw4_k<<<dim3(512, 4), blk, 0, stream>>>(Wq, Wk, Wv, Wo, w4);
  qkvproj_k<<<dim3(512, 3), blk, 0, stream>>>(query, key, value, w4,
                                              bq, bk, bv, qp, kp, vt);

  short* ctxPlane;
  if (fuse) {
    attn_k<true><<<dim3(2048), blk, 0, stream>>>(qp, kp, vt, attn, cx);
    ctxPlane = cx;
  } else {
    attn_k<false><<<dim3(2048), blk, 0, stream>>>(qp, kp, vt, attn, nullptr);
    // ctx aliases Q plane — safe across kernel boundary (Q dead now)
    pv2_k<<<dim3(2048), blk, 0, stream>>>(attn, vt, qp);
    ctxPlane = qp;
  }

  oproj_k<<<dim3(512), blk, 0, stream>>>(ctxPlane, w4 + 3 * WPLANE, bo, out);
}